// Round 5
// baseline (410.914 us; speedup 1.0000x reference)
//
#include <hip/hip_runtime.h>
#include <hip/hip_bf16.h>
#include <math.h>

typedef __bf16 bf16_t;
typedef __bf16 bf16x4 __attribute__((ext_vector_type(4)));
typedef __bf16 bf16x8 __attribute__((ext_vector_type(8)));
typedef float f32x4 __attribute__((ext_vector_type(4)));
typedef unsigned int u32x4 __attribute__((ext_vector_type(4)));

#define T_DIM 2048
#define C_DIM 2048
#define NH 16
#define HS 128
#define NLQ 1536
#define NLKV 512
#define DHR 64
#define QKD 192  // HS + DHR

// flash work decomposition: per (head, qt) the 2qt+2 KV tiles are split into
// 1/2/3 balanced chunks (max span 12); slots ordered longest-first.
__constant__ int c_qt_tab[30] = {5,11,11,15,15,10,10,15,14,14,14,9,9,13,4,
                                 13,13,8,8,12,12,12,3,7,7,6,6,2,1,0};
__constant__ int c_pt_tab[30] = {0,0,1,0,1,0,1,2,0,1,2,0,1,0,0,
                                 1,2,0,1,0,1,2,0,0,1,0,1,0,0,0};
__constant__ int c_pbase[16]  = {0,0,0,0,0,0,0,2,4,6,8,10,12,15,18,21};

#define NSLOT_A 338  // Opart slots in region A; rest in region B

// inline dtype probe: true (f32 inputs) iff reading x as bf16 yields huge/NaN.
__device__ __forceinline__ int probe_f32(const bf16_t* __restrict__ x) {
  int lane = threadIdx.x & 63;
  int bad = 0;
#pragma unroll
  for (int i = 0; i < 4; ++i) {
    float v = (float)x[lane + i * 64];
    if (!(fabsf(v) < 1.0e6f)) bad = 1;
  }
  return (__ballot(bad) != 0ull) ? 1 : 0;
}

__device__ __forceinline__ float* opart_at(float* A, float* B, int pi) {
  return (pi < NSLOT_A) ? (A + (size_t)pi * 16384) : (B + (size_t)(pi - NSLOT_A) * 16384);
}
__device__ __forceinline__ const float* opart_atc(const float* A, const float* B, int pi) {
  return (pi < NSLOT_A) ? (A + (size_t)pi * 16384) : (B + (size_t)(pi - NSLOT_A) * 16384);
}

// ---------------------------------------------------------------- prep: 9 converts + 2 transposes
struct PrepPack {
  const void* src[9];
  bf16_t* dst[9];
  int n[9];
  const void* tsrc[2];
  bf16_t* tdst[2];
  int tR[2], tC[2], tbx[2];  // in R x C -> out C x R; tbx = C/32
};

__global__ __launch_bounds__(256) void prep_k(PrepPack p, const bf16_t* __restrict__ xprobe) {
  __shared__ bf16_t tile[32][33];
  const int f32 = probe_f32(xprobe);
  const int which = blockIdx.y;
  if (which < 9) {
    const int n = p.n[which];
    const int stride = gridDim.x * 256 * 8;
    for (int i = (blockIdx.x * 256 + threadIdx.x) * 8; i < n; i += stride) {
      if (f32) {
        const float* s = (const float*)p.src[which] + i;
        f32x4 lo = *(const f32x4*)s;
        f32x4 hi = *(const f32x4*)(s + 4);
        bf16x8 v;
#pragma unroll
        for (int j = 0; j < 4; ++j) { v[j] = (bf16_t)lo[j]; v[j + 4] = (bf16_t)hi[j]; }
        *(bf16x8*)(p.dst[which] + i) = v;
      } else {
        *(bf16x8*)(p.dst[which] + i) = *(const bf16x8*)((const bf16_t*)p.src[which] + i);
      }
    }
  } else {
    const int ts = which - 9;
    const int R = p.tR[ts], C = p.tC[ts], tbx = p.tbx[ts];
    const int ntiles = tbx * (R / 32);
    if ((int)blockIdx.x >= ntiles) return;
    const void* in = p.tsrc[ts];
    bf16_t* out = p.tdst[ts];
    int bx = (blockIdx.x % tbx) * 32, by = (blockIdx.x / tbx) * 32;
    int tx = threadIdx.x & 31, ty = threadIdx.x >> 5;  // 32 x 8
    for (int i = ty; i < 32; i += 8) {
      int r = by + i, c = bx + tx;
      size_t idx = (size_t)r * C + c;
      tile[i][tx] = f32 ? (bf16_t)((const float*)in)[idx] : ((const bf16_t*)in)[idx];
    }
    __syncthreads();
    for (int i = ty; i < 32; i += 8) {
      int r = bx + i, c = by + tx;  // out[r][c] = in[c][r]
      out[(size_t)r * R + c] = tile[tx][i];
    }
  }
}

// ---------------------------------------------------------------- async global->LDS (16B)
__device__ __forceinline__ void async16(const bf16_t* g, bf16_t* l) {
  __builtin_amdgcn_global_load_lds(
      (const __attribute__((address_space(1))) void*)g,
      (__attribute__((address_space(3))) void*)l, 16, 0, 0);
}

__device__ __forceinline__ float fexp2(float x) {
  return __builtin_amdgcn_exp2f(x);
}

// ---------------------------------------------------------------- grouped GEMM  C = A @ B^T
// 2-phase double-buffered pipeline (T3 minimum template), BK=64, XOR-swizzled LDS.
#define BM 128
#define BN 128
#define BKG 64

struct GDesc {
  const bf16_t* A; const bf16_t* B; bf16_t* C;
  int M, N, K, lda, ldb, ldc, mb, bx0;
};
struct GGrp { GDesc d[3]; };

__global__ __launch_bounds__(256) void gemm_group(GGrp g, int nseg) {
  int bx = blockIdx.x;
  int s = 0;
  while (s + 1 < nseg && bx >= g.d[s + 1].bx0) ++s;
  const GDesc D = g.d[s];
  const int local = bx - D.bx0;
  const int bm = (local % D.mb) * BM, bn = (local / D.mb) * BN;

  __shared__ bf16_t As[2][BM * BKG];  // 16 KB x2
  __shared__ bf16_t Bs[2][BN * BKG];  // 16 KB x2  (total 64 KB -> 2 blocks/CU)
  const int tid = threadIdx.x;
  const int lane = tid & 63;
  const int wave = tid >> 6;
  const int l16 = lane & 15, quad = lane >> 4;
  const int wm = (wave >> 1) * 64, wn = (wave & 1) * 64;
  f32x4 acc[4][4] = {};

  const int nt = D.K / BKG;

  // prologue: stage tile 0 into buffer 0
#pragma unroll
  for (int r = 0; r < 4; ++r) {
    int c = r * 256 + tid;           // 16B chunk 0..1023, row-major [128][8]
    int row = c >> 3;
    int c8 = (c & 7) ^ (row & 7);    // inverse swizzle on the global source
    int ar = bm + row; if (ar > D.M - 1) ar = D.M - 1;
    int br = bn + row; if (br > D.N - 1) br = D.N - 1;
    async16(D.A + (size_t)ar * D.lda + c8 * 8, &As[0][c * 8]);
    async16(D.B + (size_t)br * D.ldb + c8 * 8, &Bs[0][c * 8]);
  }
  asm volatile("s_waitcnt vmcnt(0)" ::: "memory");
  __builtin_amdgcn_s_barrier();

  for (int t = 0; t < nt; ++t) {
    const int cur = t & 1;
    if (t + 1 < nt) {
      const int k0 = (t + 1) * BKG;
#pragma unroll
      for (int r = 0; r < 4; ++r) {
        int c = r * 256 + tid;
        int row = c >> 3;
        int c8 = (c & 7) ^ (row & 7);
        int ar = bm + row; if (ar > D.M - 1) ar = D.M - 1;
        int br = bn + row; if (br > D.N - 1) br = D.N - 1;
        async16(D.A + (size_t)ar * D.lda + k0 + c8 * 8, &As[cur ^ 1][c * 8]);
        async16(D.B + (size_t)br * D.ldb + k0 + c8 * 8, &Bs[cur ^ 1][c * 8]);
      }
    }
#pragma unroll
    for (int kk = 0; kk < 2; ++kk) {
      bf16x8 af[4], bfr[4];
#pragma unroll
      for (int i = 0; i < 4; ++i) {
        int row = wm + i * 16 + l16;
        af[i] = *(const bf16x8*)(&As[cur][row * BKG + (((kk * 4 + quad) ^ (row & 7)) * 8)]);
      }
#pragma unroll
      for (int j = 0; j < 4; ++j) {
        int row = wn + j * 16 + l16;
        bfr[j] = *(const bf16x8*)(&Bs[cur][row * BKG + (((kk * 4 + quad) ^ (row & 7)) * 8)]);
      }
#pragma unroll
      for (int i = 0; i < 4; ++i)
#pragma unroll
        for (int j = 0; j < 4; ++j)
          acc[i][j] = __builtin_amdgcn_mfma_f32_16x16x32_bf16(af[i], bfr[j], acc[i][j], 0, 0, 0);
    }
    asm volatile("s_waitcnt vmcnt(0)" ::: "memory");
    __builtin_amdgcn_s_barrier();
  }

#pragma unroll
  for (int i = 0; i < 4; ++i)
#pragma unroll
    for (int j = 0; j < 4; ++j)
#pragma unroll
      for (int r = 0; r < 4; ++r) {
        int gm = bm + wm + i * 16 + quad * 4 + r;
        int gn = bn + wn + j * 16 + l16;
        if (gm < D.M && gn < D.N) D.C[(size_t)gm * D.ldc + gn] = (bf16_t)acc[i][j][r];
      }
}

// ---------------------------------------------------------------- fused pack + rope
__global__ void pack_qk_k(const bf16_t* __restrict__ qcat, const bf16_t* __restrict__ khead,
                          const bf16_t* __restrict__ xa,
                          const bf16_t* __restrict__ fc, const bf16_t* __restrict__ fs,
                          bf16_t* __restrict__ Qp, bf16_t* __restrict__ Kp) {
  int idx = blockIdx.x * blockDim.x + threadIdx.x;
  if (idx >= NH * T_DIM * 96) return;
  int j = idx % 96;
  int t = (idx / 96) % T_DIM;
  int h = idx / (96 * T_DIM);
  if (blockIdx.y == 0) {
    const float scale = 0.07216878364870323f;  // 1/sqrt(HS+DHR)
    bf16_t* out = Qp + ((size_t)h * T_DIM + t) * QKD;
    if (j < 64) {
      float a = (float)qcat[(size_t)t * 3072 + h * HS + 2 * j];
      float b = (float)qcat[(size_t)t * 3072 + h * HS + 2 * j + 1];
      out[2 * j] = (bf16_t)(a * scale);
      out[2 * j + 1] = (bf16_t)(b * scale);
    } else {
      int i = j - 64;
      float re = (float)qcat[(size_t)t * 3072 + 2048 + h * DHR + 2 * i];
      float im = (float)qcat[(size_t)t * 3072 + 2048 + h * DHR + 2 * i + 1];
      float c = (float)fc[t * 32 + i], s = (float)fs[t * 32 + i];
      out[HS + 2 * i] = (bf16_t)((re * c - im * s) * scale);
      out[HS + 2 * i + 1] = (bf16_t)((re * s + im * c) * scale);
    }
  } else {
    bf16_t* out = Kp + ((size_t)h * T_DIM + t) * QKD;
    if (j < 64) {
      out[2 * j] = khead[(size_t)t * C_DIM + h * HS + 2 * j];
      out[2 * j + 1] = khead[(size_t)t * C_DIM + h * HS + 2 * j + 1];
    } else {
      int i = j - 64;
      float re = (float)xa[(size_t)t * 2112 + 2048 + 2 * i];
      float im = (float)xa[(size_t)t * 2112 + 2048 + 2 * i + 1];
      float c = (float)fc[t * 32 + i], s = (float)fs[t * 32 + i];
      out[HS + 2 * i] = (bf16_t)(re * c - im * s);
      out[HS + 2 * i + 1] = (bf16_t)(re * s + im * c);
    }
  }
}

// ---------------------------------------------------------------- flash attention
// S^T orientation, 4 waves x 32 t-rows, FBM=128, FBN=64, balanced KV-split (<=12 tiles),
// XCD-pinned block id: id = xcd + 8*slot; h = xcd + 8*(slot/30); p = slot%30.
// Reg-staged double-buffer (cross-iteration overlap) + in-register P via shfl
// (no Psm) -> LDS 44 KB -> 3 blocks/CU.
#define FBM 128
#define FBN 64
#define KPITCH 200
#define VPITCH 72

__global__ __launch_bounds__(256, 3) void flash_k(const bf16_t* __restrict__ Qp,
                                                  const bf16_t* __restrict__ Kp,
                                                  const bf16_t* __restrict__ VT,
                                                  void* __restrict__ Y,
                                                  const bf16_t* __restrict__ xprobe,
                                                  float* __restrict__ OpartA,
                                                  float* __restrict__ OpartB,
                                                  float* __restrict__ Mpart,
                                                  float* __restrict__ Lpart) {
  __shared__ bf16_t Ksm[FBN * KPITCH];    // 25.6 KB
  __shared__ bf16_t Vtsm[HS * VPITCH];    // 18.4 KB
  const int tid = threadIdx.x;
  const int lane = tid & 63, wave = tid >> 6;  // wave 0..3, 32 t-rows each
  const int l16 = lane & 15, quad = lane >> 4;
  const int id = blockIdx.x;
  const int xcd = id & 7, slot = id >> 3;
  const int h = xcd + 8 * (slot / 30);
  const int p = slot % 30;
  const int qt = c_qt_tab[p];
  const int part = c_pt_tab[p];
  const int nkv = 2 * qt + 2;
  const int nparts = (qt <= 5) ? 1 : (qt <= 11 ? 2 : 3);
  const int bse = nkv / nparts, rem = nkv % nparts;
  const int kt0 = part * bse + (part < rem ? part : rem);
  const int kt1 = kt0 + bse + (part < rem ? 1 : 0);
  const int partial = (nparts > 1);
  const int qb = qt * FBM;
  const int f32out = probe_f32(xprobe);
  const float L2E = 1.4426950408889634f;
  // P redistribution lanes: words 0,1 from srcA, words 2,3 from srcB;
  // value pk32[2*s2 + hi][c], hi = quad>>1. (HW-verified mapping, round 4.)
  const int srcA = l16 + ((lane & 16) << 1);  // l16 + 32*(quad&1)
  const int srcB = srcA + 16;
  const int hi = quad >> 1;

  // Q fragments: two 16-row t-tiles per wave (B-operand: n=l16 rows)
  bf16x8 aq[2][6];
#pragma unroll
  for (int tt = 0; tt < 2; ++tt) {
    const bf16_t* qbase = Qp + ((size_t)h * T_DIM + qb + wave * 32 + tt * 16 + l16) * QKD;
#pragma unroll
    for (int c = 0; c < 6; ++c) aq[tt][c] = *(const bf16x8*)(qbase + c * 32 + quad * 8);
  }

  f32x4 o[2][8] = {};           // O^T: rows d (8 tiles), cols t (l16); [tt]
  float m_i[2] = {-3.0e38f, -3.0e38f}, l_i[2] = {0.f, 0.f};

  const bf16_t* kg_base = Kp + (size_t)h * T_DIM * QKD;
  const bf16_t* vg_base = VT + (size_t)(h * HS) * T_DIM;

  // register prefetch (6 K-chunks + 4 V-chunks per thread, 256 threads)
  bf16x8 kreg[6], vreg[4];
  {
    const bf16_t* kg = kg_base + (size_t)kt0 * FBN * QKD;
#pragma unroll
    for (int i = 0; i < 6; ++i) {
      int idx = i * 256 + tid;  // 64 rows * 24 vec8
      kreg[i] = *(const bf16x8*)(kg + (size_t)idx * 8);
    }
    const bf16_t* vg = vg_base + kt0 * FBN;
#pragma unroll
    for (int i = 0; i < 4; ++i) {
      int idx = i * 256 + tid, row = idx >> 3, c8 = idx & 7;
      vreg[i] = *(const bf16x8*)(vg + (size_t)row * T_DIM + c8 * 8);
    }
  }

  for (int kt = kt0; kt < kt1; ++kt) {
    __syncthreads();  // previous compute done -> LDS writable
#pragma unroll
    for (int i = 0; i < 6; ++i) {
      int idx = i * 256 + tid, row = idx / 24, c8 = idx % 24;
      *(bf16x8*)(Ksm + row * KPITCH + c8 * 8) = kreg[i];
    }
#pragma unroll
    for (int i = 0; i < 4; ++i) {
      int idx = i * 256 + tid, row = idx >> 3, c8 = idx & 7;
      *(bf16x8*)(Vtsm + row * VPITCH + c8 * 8) = vreg[i];
    }
    __syncthreads();  // LDS ready
    if (kt + 1 < kt1) {
      const bf16_t* kg = kg_base + (size_t)(kt + 1) * FBN * QKD;
#pragma unroll
      for (int i = 0; i < 6; ++i) {
        int idx = i * 256 + tid;
        kreg[i] = *(const bf16x8*)(kg + (size_t)idx * 8);
      }
      const bf16_t* vg = vg_base + (kt + 1) * FBN;
#pragma unroll
      for (int i = 0; i < 4; ++i) {
        int idx = i * 256 + tid, row = idx >> 3, c8 = idx & 7;
        vreg[i] = *(const bf16x8*)(vg + (size_t)row * T_DIM + c8 * 8);
      }
    }
    // S^T = K @ Q^T : rows s (4 tiles of 16), cols t (2 tiles, l16)
    f32x4 sc[2][4] = {};
    __builtin_amdgcn_s_setprio(1);
#pragma unroll
    for (int nt = 0; nt < 4; ++nt)
#pragma unroll
      for (int c = 0; c < 6; ++c) {
        bf16x8 bk = *(const bf16x8*)(Ksm + (nt * 16 + l16) * KPITCH + c * 32 + quad * 8);
        sc[0][nt] = __builtin_amdgcn_mfma_f32_16x16x32_bf16(bk, aq[0][c], sc[0][nt], 0, 0, 0);
        sc[1][nt] = __builtin_amdgcn_mfma_f32_16x16x32_bf16(bk, aq[1][c], sc[1][nt], 0, 0, 0);
      }
    __builtin_amdgcn_s_setprio(0);
    if (kt >= 2 * qt) {  // diagonal region
#pragma unroll
      for (int tt = 0; tt < 2; ++tt) {
        int t_glob = qb + wave * 32 + tt * 16 + l16;
#pragma unroll
        for (int nt = 0; nt < 4; ++nt) {
          int s_base = kt * FBN + nt * 16 + quad * 4;
#pragma unroll
          for (int r = 0; r < 4; ++r)
            if (s_base + r > t_glob) sc[tt][nt][r] = -3.0e38f;
        }
      }
    }
    // online softmax per t-column (l16); defer-max (T13); P packed in-register
    unsigned int pk32[2][4][2];
#pragma unroll
    for (int tt = 0; tt < 2; ++tt) {
      float mx = sc[tt][0][0];
#pragma unroll
      for (int nt = 0; nt < 4; ++nt)
#pragma unroll
        for (int r = 0; r < 4; ++r) mx = fmaxf(mx, sc[tt][nt][r]);
      mx = fmaxf(mx, __shfl_xor(mx, 16, 64));
      mx = fmaxf(mx, __shfl_xor(mx, 32, 64));
      int need = (mx > m_i[tt] + 5.5f) ? 1 : 0;
      if (__any(need)) {
        float mn = fmaxf(m_i[tt], mx);
        float alpha = fexp2((m_i[tt] - mn) * L2E);
        m_i[tt] = mn;
        l_i[tt] *= alpha;
#pragma unroll
        for (int dt = 0; dt < 8; ++dt) o[tt][dt] *= alpha;
      }
      float rs = 0.f;
#pragma unroll
      for (int nt = 0; nt < 4; ++nt) {
        float p0 = fexp2((sc[tt][nt][0] - m_i[tt]) * L2E);
        float p1 = fexp2((sc[tt][nt][1] - m_i[tt]) * L2E);
        float p2 = fexp2((sc[tt][nt][2] - m_i[tt]) * L2E);
        float p3 = fexp2((sc[tt][nt][3] - m_i[tt]) * L2E);
        rs += (p0 + p1) + (p2 + p3);
        asm("v_cvt_pk_bf16_f32 %0, %1, %2" : "=v"(pk32[tt][nt][0]) : "v"(p0), "v"(p1));
        asm("v_cvt_pk_bf16_f32 %0, %1, %2" : "=v"(pk32[tt][nt][1]) : "v"(p2), "v"(p3));
      }
      rs += __shfl_xor(rs, 16, 64);
      rs += __shfl_xor(rs, 32, 64);
      l_i[tt] += rs;
    }
    // O^T += V^T @ P^T; P B-fragments assembled in-register via shfl.
    __builtin_amdgcn_s_setprio(1);
#pragma unroll
    for (int s2 = 0; s2 < 2; ++s2) {
      u32x4 wa, wb;
#pragma unroll
      for (int c = 0; c < 2; ++c) {
        unsigned int a0 = (unsigned int)__shfl((int)pk32[0][2 * s2][c], srcA, 64);
        unsigned int a1 = (unsigned int)__shfl((int)pk32[0][2 * s2 + 1][c], srcA, 64);
        wa[c] = hi ? a1 : a0;
        unsigned int a2 = (unsigned int)__shfl((int)pk32[0][2 * s2][c], srcB, 64);
        unsigned int a3 = (unsigned int)__shfl((int)pk32[0][2 * s2 + 1][c], srcB, 64);
        wa[2 + c] = hi ? a3 : a2;
        unsigned int b0 = (unsigned int)__shfl((int)pk32[1][2 * s2][c], srcA, 64);
        unsigned int b1 = (unsigned int)__shfl((int)pk32[1][2 * s2 + 1][c], srcA, 64);
        wb[c] = hi ? b1 : b0;
        unsigned int b2 = (unsigned int)__shfl((int)pk32[1][2 * s2][c], srcB, 64);
        unsigned int b3 = (unsigned int)__shfl((int)pk32[1][2 * s2 + 1][c], srcB, 64);
        wb[2 + c] = hi ? b3 : b2;
      }
      bf16x8 ap0 = __builtin_bit_cast(bf16x8, wa);
      bf16x8 ap1 = __builtin_bit_cast(bf16x8, wb);
#pragma unroll
      for (int dt = 0; dt < 8; ++dt) {
        bf16x8 bv = *(const bf16x8*)(Vtsm + (dt * 16 + l16) * VPITCH + s2 * 32 + quad * 8);
        o[0][dt] = __builtin_amdgcn_mfma_f32_16x16x32_bf16(bv, ap0, o[0][dt], 0, 0, 0);
        o[1][dt] = __builtin_amdgcn_mfma_f32_16x16x32_bf16(bv, ap1, o[1][dt], 0, 0, 0);
      }
    }
    __builtin_amdgcn_s_setprio(0);
  }

  if (!partial) {
#pragma unroll
    for (int tt = 0; tt < 2; ++tt) {
      float inv = 1.0f / l_i[tt];
      int t = qb + wave * 32 + tt * 16 + l16;
#pragma unroll
      for (int dt = 0; dt < 8; ++dt) {
        size_t oi = (size_t)t * C_DIM + h * HS + dt * 16 + quad * 4;
        if (f32out) {
          f32x4 v;
#pragma unroll
          for (int r = 0; r < 4; ++r) v[r] = o[tt][dt][r] * inv;
          *(f32x4*)((float*)Y + oi) = v;
        } else {
          bf16x4 v;
#pragma unroll
          for (int r = 0; r < 4; ++r) v[r] = (bf16_t)(o[tt][dt][r] * inv);
          *(bf16x4*)((bf16_t*)Y + oi) = v;
        }
      }
    }
  } else {
    const int pi = h * 24 + c_pbase[qt] + part;
    float* obase = opart_at(OpartA, OpartB, pi);
#pragma unroll
    for (int tt = 0; tt < 2; ++tt) {
      int rowl = wave * 32 + tt * 16 + l16;  // 0..127
      float* ob = obase + (size_t)rowl * 128;
#pragma unroll
      for (int dt = 0; dt < 8; ++dt) {
        f32x4 v = o[tt][dt];
        *(f32x4*)(ob + dt * 16 + quad * 4) = v;
      }
      if (quad == 0) {
        Mpart[(size_t)pi * 128 + rowl] = m_i[tt];
        Lpart[(size_t)pi * 128 + rowl] = l_i[tt];
      }
    }
  }
}

// ---------------------------------------------------------------- combine partials (qt>=6)
__global__ __launch_bounds__(256) void combine_k(const float* __restrict__ OpartA,
                                                 const float* __restrict__ OpartB,
                                                 const float* __restrict__ Mpart,
                                                 const float* __restrict__ Lpart,
                                                 void* __restrict__ Y,
                                                 const bf16_t* __restrict__ xprobe) {
  const int h = blockIdx.y;
  const int qt = 6 + blockIdx.x;       // 6..15
  const int c = (qt <= 11) ? 2 : 3;
  const int pib = h * 24 + c_pbase[qt];
  const int row = threadIdx.x >> 1;    // 0..127
  const int c0 = (threadIdx.x & 1) * 64;
  const int f32out = probe_f32(xprobe);
  const float L2E = 1.4426950408889634f;
  float m0 = Mpart[(size_t)pib * 128 + row];
  float m1 = Mpart[(size_t)(pib + 1) * 128 + row];
  float l0 = Lpart[(size_t)pib * 128 + row];
  float l1 = Lpart[(size_t)(pib + 1) * 128 + row];
  float m2 = -3.0e38f, l2 = 0.f;
  if (c == 3) {
    m2 = Mpart[(size_t)(pib + 2) * 128 + row];
    l2 = Lpart[(size_t)(pib + 2) * 128 + row];
  }
  float ms = fmaxf(m0, fmaxf(m1, m2));
  float w0 = fexp2((m0 - ms) * L2E);
  float w1 = fexp2((m1 - ms) * L2E);
  float w2 = fexp2((m2 - ms) * L2E);
  float inv = 1.0f / (l0 * w0 + l1 * w1 + l2 * w2);
  const float* O0 = opart_atc(OpartA, OpartB, pib) + (size_t)row * 128 + c0;
  const float* O1 = opart_atc(OpartA, OpartB, pib + 1) + (size_t)row * 128 + c0;
  const float* O2 = opart_atc(OpartA, OpartB, pib + 2) + (size_t)row * 128 + c0;
  int t = qt * 128 + row;
  size_t ob = (size_t)t * C_DIM + h * HS + c0;
#pragma unroll
  for (int d4 = 0; d4 < 64; d4 += 4) {
    f32x4 a = *(const f32x4*)(O0 + d4);
    f32x4 b = *(const f32x4*)(O1 + d4);
    f32x4 acc;
#pragma unroll
    for (int j = 0; j < 4; ++j) acc[j] = a[j] * w0 + b[j] * w1;
    if (c == 3) {
      f32x4 e = *(const f32x4*)(O2 + d4);
#pragma unroll
      for (int j = 0; j < 4; ++j) acc[j] += e[j] * w2;
    }
#pragma unroll
    for (int j = 0; j < 4; ++j) {
      float v = acc[j] * inv;
      if (f32out) ((float*)Y)[ob + d4 + j] = v;
      else        ((bf16_t*)Y)[ob + d4 + j] = (bf16_t)v;
    }
  }
}

// ---------------------------------------------------------------- launch
extern "C" void kernel_launch(void* const* d_in, const int* in_sizes, int n_in,
                              void* d_out, int out_size, void* d_ws, size_t ws_size,
                              hipStream_t stream) {
  bf16_t* w = (bf16_t*)d_ws;
  const bf16_t* xprobe = (const bf16_t*)d_in[0];

  if (ws_size < (size_t)34472000 * 2 + 128) return;

  // ---- workspace layout (bf16 elements), lifetime-aliased ----
  bf16_t* fcc    = w + 64;        // 65536
  bf16_t* fsc    = w + 65600;     // 65536
  bf16_t* xc     = w + 131136;    // 4194304
  bf16_t* BigB   = w + 4325440;   // 4325376 = [W_dq(1536) | W_dkv(512) | W_kr(64)] x 2048
  bf16_t* dqc    = BigB;
  bf16_t* dkvc   = BigB + 3145728;
  bf16_t* krc    = BigB + 4194304;
  bf16_t* Bq     = w + 8650816;   // 4718592 = [W_uq_t(2048) | W_qr(1024)] x 1536
  bf16_t* W_uq_t = Bq;
  bf16_t* qrc    = Bq + 3145728;
  bf16_t* xa     = w + 13369408;  // 4325376: cols [c_q(1536) | c_kv(512) | k_r(64)], ld 2112
  bf16_t* qcat   = w + 17694784;  // 6291456: cols [q_up(2048) | q_r(1024)], ld 3072
  bf16_t* k_head = w + 23986240;  // 4194304
  bf16_t* vhatT  = w + 28180544;  // 4194304
  bf16_t* ukc    = w + 32374848;  // 1048576
  bf16_t* Pt     = w + 33423424;  // 1048576
  // aliases (lifetime-disjoint)
  bf16_t* woc    = qcat;          // dead before qcat GEMM writes here
  bf16_t* W_uv_t = k_head;        // dead before k_head GEMM writes here
  bf16_t* Qpack  = xc;            // xc + BigB head; ends at elem 6422592
  bf16_t* Kpack  = qcat;          // qcat dead after pack
  // flash partials, 384 slots of 128x128 f32, split across two dead regions:
  //   region A [6422592, 17694784): slots 0..337 + Mpart/Lpart at the tail
  //   region B [23986240, 28180544) (dead k_head): slots 338..383
  float* OpartA = (float*)(w + 6422592);   // 338 slots: ends at elem 17498176
  float* Mpart  = (float*)(w + 17498176);  // 384*128 f32 -> ends 17596480
  float* Lpart  = (float*)(w + 17596480);  // -> ends 17694784 (= qcat start)
  float* OpartB = (float*)(w + 23986240);  // 46 slots: ends at elem 25493568

  // prep: 9 converts + 2 transposes, one launch
  PrepPack pp;
  const void* srcs[9] = {d_in[1], d_in[2], d_in[0], d_in[3], d_in[5], d_in[9], d_in[8], d_in[6], d_in[10]};
  bf16_t* dsts[9]     = {fcc,     fsc,     xc,      dqc,     dkvc,    krc,     qrc,     ukc,     woc};
  int ns[9] = {T_DIM * 32, T_DIM * 32, T_DIM * C_DIM, NLQ * C_DIM, NLKV * C_DIM,
               DHR * C_DIM, NH * DHR * NLQ, C_DIM * NLKV, C_DIM * C_DIM};
  for (int i = 0; i < 9; ++i) { pp.src[i] = srcs[i]; pp.dst[i] = dsts[i]; pp.n[i] = ns[i]; }
  pp.tsrc[0] = d_in[4]; pp.tdst[0] = W_uq_t; pp.tR[0] = 1536; pp.tC[0] = 2048; pp.tbx[0] = 64;
  pp.tsrc[1] = d_in[7]; pp.tdst[1] = W_uv_t; pp.tR[1] = 2048; pp.tC[1] = 512;  pp.tbx[1] = 16;
  prep_k<<<dim3(3072, 11), 256, 0, stream>>>(pp, xprobe);

  // G1: xa (272 blk) || Pt (64 blk)
  {
    GGrp g;
    g.d[0] = {xc,  BigB,   xa, 2048, 2112, 2048, 2048, 2048, 2112, 16, 0};
    g.d[1] = {woc, W_uv_t, Pt, 2048,  512, 2048, 2048, 2048,  512, 16, 272};
    gemm_group<<<336, 256, 0, stream>>>(g, 2);
  }
  // G2: qcat (384) || k_head (256) || vhatT (256)
  {
    GGrp g;
    g.d[0] = {xa,        Bq,        qcat,   2048, 3072, 1536, 2112, 1536, 3072, 16, 0};
    g.d[1] = {xa + 1536, ukc,       k_head, 2048, 2048,  512, 2112,  512, 2048, 16, 384};
    g.d[2] = {Pt,        xa + 1536, vhatT,  2048, 2048,  512,  512, 2112, 2048, 16, 640};
    gemm_group<<<896, 256, 0, stream>>>(g, 3);
  }

  int pk = (NH * T_DIM * 96 + 255) / 256;
  pack_qk_k<<<dim3(pk, 2), 256, 0, stream>>>(qcat, k_head, xa, fcc, fsc, Qpack, Kpack);

  flash_k<<<dim3(480), 256, 0, stream>>>(Qpack, Kpack, vhatT, d_out, xprobe,
                                         OpartA, OpartB, Mpart, Lpart);
  combine_k<<<dim3(10, NH), 256, 0, stream>>>(OpartA, OpartB, Mpart, Lpart, d_out, xprobe);
}

// Round 6
// 319.250 us; speedup vs baseline: 1.2871x; 1.2871x over previous
//
#include <hip/hip_runtime.h>
#include <hip/hip_bf16.h>
#include <math.h>

typedef __bf16 bf16_t;
typedef __bf16 bf16x4 __attribute__((ext_vector_type(4)));
typedef __bf16 bf16x8 __attribute__((ext_vector_type(8)));
typedef float f32x4 __attribute__((ext_vector_type(4)));
typedef unsigned int u32x4 __attribute__((ext_vector_type(4)));

#define T_DIM 2048
#define C_DIM 2048
#define NH 16
#define HS 128
#define NLQ 1536
#define NLKV 512
#define DHR 64
#define QKD 192  // HS + DHR

// flash work decomposition: per (head, qt) the 2qt+2 KV tiles are split into
// 1/2/3 balanced chunks (max span 12); slots ordered longest-first.
__constant__ int c_qt_tab[30] = {5,11,11,15,15,10,10,15,14,14,14,9,9,13,4,
                                 13,13,8,8,12,12,12,3,7,7,6,6,2,1,0};
__constant__ int c_pt_tab[30] = {0,0,1,0,1,0,1,2,0,1,2,0,1,0,0,
                                 1,2,0,1,0,1,2,0,0,1,0,1,0,0,0};
__constant__ int c_pbase[16]  = {0,0,0,0,0,0,0,2,4,6,8,10,12,15,18,21};

#define NSLOT_A 338  // Opart slots in region A; rest in region B

// inline dtype probe: true (f32 inputs) iff reading x as bf16 yields huge/NaN.
__device__ __forceinline__ int probe_f32(const bf16_t* __restrict__ x) {
  int lane = threadIdx.x & 63;
  int bad = 0;
#pragma unroll
  for (int i = 0; i < 4; ++i) {
    float v = (float)x[lane + i * 64];
    if (!(fabsf(v) < 1.0e6f)) bad = 1;
  }
  return (__ballot(bad) != 0ull) ? 1 : 0;
}

__device__ __forceinline__ float* opart_at(float* A, float* B, int pi) {
  return (pi < NSLOT_A) ? (A + (size_t)pi * 16384) : (B + (size_t)(pi - NSLOT_A) * 16384);
}
__device__ __forceinline__ const float* opart_atc(const float* A, const float* B, int pi) {
  return (pi < NSLOT_A) ? (A + (size_t)pi * 16384) : (B + (size_t)(pi - NSLOT_A) * 16384);
}

// ---------------------------------------------------------------- prep: 9 converts + 2 transposes
struct PrepPack {
  const void* src[9];
  bf16_t* dst[9];
  int n[9];
  const void* tsrc[2];
  bf16_t* tdst[2];
  int tR[2], tC[2], tbx[2];  // in R x C -> out C x R; tbx = C/32
};

__global__ __launch_bounds__(256) void prep_k(PrepPack p, const bf16_t* __restrict__ xprobe) {
  __shared__ bf16_t tile[32][33];
  const int f32 = probe_f32(xprobe);
  const int which = blockIdx.y;
  if (which < 9) {
    const int n = p.n[which];
    const int stride = gridDim.x * 256 * 8;
    for (int i = (blockIdx.x * 256 + threadIdx.x) * 8; i < n; i += stride) {
      if (f32) {
        const float* s = (const float*)p.src[which] + i;
        f32x4 lo = *(const f32x4*)s;
        f32x4 hi = *(const f32x4*)(s + 4);
        bf16x8 v;
#pragma unroll
        for (int j = 0; j < 4; ++j) { v[j] = (bf16_t)lo[j]; v[j + 4] = (bf16_t)hi[j]; }
        *(bf16x8*)(p.dst[which] + i) = v;
      } else {
        *(bf16x8*)(p.dst[which] + i) = *(const bf16x8*)((const bf16_t*)p.src[which] + i);
      }
    }
  } else {
    const int ts = which - 9;
    const int R = p.tR[ts], C = p.tC[ts], tbx = p.tbx[ts];
    const int ntiles = tbx * (R / 32);
    if ((int)blockIdx.x >= ntiles) return;
    const void* in = p.tsrc[ts];
    bf16_t* out = p.tdst[ts];
    int bx = (blockIdx.x % tbx) * 32, by = (blockIdx.x / tbx) * 32;
    int tx = threadIdx.x & 31, ty = threadIdx.x >> 5;  // 32 x 8
    for (int i = ty; i < 32; i += 8) {
      int r = by + i, c = bx + tx;
      size_t idx = (size_t)r * C + c;
      tile[i][tx] = f32 ? (bf16_t)((const float*)in)[idx] : ((const bf16_t*)in)[idx];
    }
    __syncthreads();
    for (int i = ty; i < 32; i += 8) {
      int r = bx + i, c = by + tx;  // out[r][c] = in[c][r]
      out[(size_t)r * R + c] = tile[tx][i];
    }
  }
}

// ---------------------------------------------------------------- async global->LDS (16B)
__device__ __forceinline__ void async16(const bf16_t* g, bf16_t* l) {
  __builtin_amdgcn_global_load_lds(
      (const __attribute__((address_space(1))) void*)g,
      (__attribute__((address_space(3))) void*)l, 16, 0, 0);
}

__device__ __forceinline__ float fexp2(float x) {
  return __builtin_amdgcn_exp2f(x);
}

// ---------------------------------------------------------------- grouped GEMM  C = A @ B^T
// 2-phase double-buffered pipeline (T3 minimum template), BK=64, XOR-swizzled LDS.
#define BM 128
#define BN 128
#define BKG 64

struct GDesc {
  const bf16_t* A; const bf16_t* B; bf16_t* C;
  int M, N, K, lda, ldb, ldc, mb, bx0;
};
struct GGrp { GDesc d[3]; };

__global__ __launch_bounds__(256) void gemm_group(GGrp g, int nseg) {
  int bx = blockIdx.x;
  int s = 0;
  while (s + 1 < nseg && bx >= g.d[s + 1].bx0) ++s;
  const GDesc D = g.d[s];
  const int local = bx - D.bx0;
  const int bm = (local % D.mb) * BM, bn = (local / D.mb) * BN;

  __shared__ bf16_t As[2][BM * BKG];  // 16 KB x2
  __shared__ bf16_t Bs[2][BN * BKG];  // 16 KB x2  (total 64 KB -> 2 blocks/CU)
  const int tid = threadIdx.x;
  const int lane = tid & 63;
  const int wave = tid >> 6;
  const int l16 = lane & 15, quad = lane >> 4;
  const int wm = (wave >> 1) * 64, wn = (wave & 1) * 64;
  f32x4 acc[4][4] = {};

  const int nt = D.K / BKG;

  // prologue: stage tile 0 into buffer 0
#pragma unroll
  for (int r = 0; r < 4; ++r) {
    int c = r * 256 + tid;           // 16B chunk 0..1023, row-major [128][8]
    int row = c >> 3;
    int c8 = (c & 7) ^ (row & 7);    // inverse swizzle on the global source
    int ar = bm + row; if (ar > D.M - 1) ar = D.M - 1;
    int br = bn + row; if (br > D.N - 1) br = D.N - 1;
    async16(D.A + (size_t)ar * D.lda + c8 * 8, &As[0][c * 8]);
    async16(D.B + (size_t)br * D.ldb + c8 * 8, &Bs[0][c * 8]);
  }
  asm volatile("s_waitcnt vmcnt(0)" ::: "memory");
  __builtin_amdgcn_s_barrier();

  for (int t = 0; t < nt; ++t) {
    const int cur = t & 1;
    if (t + 1 < nt) {
      const int k0 = (t + 1) * BKG;
#pragma unroll
      for (int r = 0; r < 4; ++r) {
        int c = r * 256 + tid;
        int row = c >> 3;
        int c8 = (c & 7) ^ (row & 7);
        int ar = bm + row; if (ar > D.M - 1) ar = D.M - 1;
        int br = bn + row; if (br > D.N - 1) br = D.N - 1;
        async16(D.A + (size_t)ar * D.lda + k0 + c8 * 8, &As[cur ^ 1][c * 8]);
        async16(D.B + (size_t)br * D.ldb + k0 + c8 * 8, &Bs[cur ^ 1][c * 8]);
      }
    }
#pragma unroll
    for (int kk = 0; kk < 2; ++kk) {
      bf16x8 af[4], bfr[4];
#pragma unroll
      for (int i = 0; i < 4; ++i) {
        int row = wm + i * 16 + l16;
        af[i] = *(const bf16x8*)(&As[cur][row * BKG + (((kk * 4 + quad) ^ (row & 7)) * 8)]);
      }
#pragma unroll
      for (int j = 0; j < 4; ++j) {
        int row = wn + j * 16 + l16;
        bfr[j] = *(const bf16x8*)(&Bs[cur][row * BKG + (((kk * 4 + quad) ^ (row & 7)) * 8)]);
      }
#pragma unroll
      for (int i = 0; i < 4; ++i)
#pragma unroll
        for (int j = 0; j < 4; ++j)
          acc[i][j] = __builtin_amdgcn_mfma_f32_16x16x32_bf16(af[i], bfr[j], acc[i][j], 0, 0, 0);
    }
    asm volatile("s_waitcnt vmcnt(0)" ::: "memory");
    __builtin_amdgcn_s_barrier();
  }

#pragma unroll
  for (int i = 0; i < 4; ++i)
#pragma unroll
    for (int j = 0; j < 4; ++j)
#pragma unroll
      for (int r = 0; r < 4; ++r) {
        int gm = bm + wm + i * 16 + quad * 4 + r;
        int gn = bn + wn + j * 16 + l16;
        if (gm < D.M && gn < D.N) D.C[(size_t)gm * D.ldc + gn] = (bf16_t)acc[i][j][r];
      }
}

// ---------------------------------------------------------------- fused pack + rope
__global__ void pack_qk_k(const bf16_t* __restrict__ qcat, const bf16_t* __restrict__ khead,
                          const bf16_t* __restrict__ xa,
                          const bf16_t* __restrict__ fc, const bf16_t* __restrict__ fs,
                          bf16_t* __restrict__ Qp, bf16_t* __restrict__ Kp) {
  int idx = blockIdx.x * blockDim.x + threadIdx.x;
  if (idx >= NH * T_DIM * 96) return;
  int j = idx % 96;
  int t = (idx / 96) % T_DIM;
  int h = idx / (96 * T_DIM);
  if (blockIdx.y == 0) {
    const float scale = 0.07216878364870323f;  // 1/sqrt(HS+DHR)
    bf16_t* out = Qp + ((size_t)h * T_DIM + t) * QKD;
    if (j < 64) {
      float a = (float)qcat[(size_t)t * 3072 + h * HS + 2 * j];
      float b = (float)qcat[(size_t)t * 3072 + h * HS + 2 * j + 1];
      out[2 * j] = (bf16_t)(a * scale);
      out[2 * j + 1] = (bf16_t)(b * scale);
    } else {
      int i = j - 64;
      float re = (float)qcat[(size_t)t * 3072 + 2048 + h * DHR + 2 * i];
      float im = (float)qcat[(size_t)t * 3072 + 2048 + h * DHR + 2 * i + 1];
      float c = (float)fc[t * 32 + i], s = (float)fs[t * 32 + i];
      out[HS + 2 * i] = (bf16_t)((re * c - im * s) * scale);
      out[HS + 2 * i + 1] = (bf16_t)((re * s + im * c) * scale);
    }
  } else {
    bf16_t* out = Kp + ((size_t)h * T_DIM + t) * QKD;
    if (j < 64) {
      out[2 * j] = khead[(size_t)t * C_DIM + h * HS + 2 * j];
      out[2 * j + 1] = khead[(size_t)t * C_DIM + h * HS + 2 * j + 1];
    } else {
      int i = j - 64;
      float re = (float)xa[(size_t)t * 2112 + 2048 + 2 * i];
      float im = (float)xa[(size_t)t * 2112 + 2048 + 2 * i + 1];
      float c = (float)fc[t * 32 + i], s = (float)fs[t * 32 + i];
      out[HS + 2 * i] = (bf16_t)(re * c - im * s);
      out[HS + 2 * i + 1] = (bf16_t)(re * s + im * c);
    }
  }
}

// ---------------------------------------------------------------- flash attention
// S^T orientation, 4 waves x 32 t-rows, FBM=128, FBN=64, balanced KV-split (<=12 tiles),
// XCD-pinned block id: id = xcd + 8*slot; h = xcd + 8*(slot/30); p = slot%30.
// Reg-staged double-buffer (cross-iteration overlap) + in-register P via shfl
// (no Psm) -> LDS 44 KB. NO launch_bounds min-waves: a reg cap forces the
// staging arrays to scratch (round-5 lesson: 84-VGPR clamp -> 410 MB spill traffic).
#define FBM 128
#define FBN 64
#define KPITCH 200
#define VPITCH 72

__global__ __launch_bounds__(256) void flash_k(const bf16_t* __restrict__ Qp,
                                               const bf16_t* __restrict__ Kp,
                                               const bf16_t* __restrict__ VT,
                                               void* __restrict__ Y,
                                               const bf16_t* __restrict__ xprobe,
                                               float* __restrict__ OpartA,
                                               float* __restrict__ OpartB,
                                               float* __restrict__ Mpart,
                                               float* __restrict__ Lpart) {
  __shared__ bf16_t Ksm[FBN * KPITCH];    // 25.6 KB
  __shared__ bf16_t Vtsm[HS * VPITCH];    // 18.4 KB
  const int tid = threadIdx.x;
  const int lane = tid & 63, wave = tid >> 6;  // wave 0..3, 32 t-rows each
  const int l16 = lane & 15, quad = lane >> 4;
  const int id = blockIdx.x;
  const int xcd = id & 7, slot = id >> 3;
  const int h = xcd + 8 * (slot / 30);
  const int p = slot % 30;
  const int qt = c_qt_tab[p];
  const int part = c_pt_tab[p];
  const int nkv = 2 * qt + 2;
  const int nparts = (qt <= 5) ? 1 : (qt <= 11 ? 2 : 3);
  const int bse = nkv / nparts, rem = nkv % nparts;
  const int kt0 = part * bse + (part < rem ? part : rem);
  const int kt1 = kt0 + bse + (part < rem ? 1 : 0);
  const int partial = (nparts > 1);
  const int qb = qt * FBM;
  const int f32out = probe_f32(xprobe);
  const float L2E = 1.4426950408889634f;
  // P redistribution lanes: words 0,1 from srcA, words 2,3 from srcB;
  // value pk32[2*s2 + hi][c], hi = quad>>1. (HW-verified mapping, rounds 4-5.)
  const int srcA = l16 + ((lane & 16) << 1);  // l16 + 32*(quad&1)
  const int srcB = srcA + 16;
  const int hi = quad >> 1;

  // Q fragments: two 16-row t-tiles per wave (B-operand: n=l16 rows)
  bf16x8 aq[2][6];
#pragma unroll
  for (int tt = 0; tt < 2; ++tt) {
    const bf16_t* qbase = Qp + ((size_t)h * T_DIM + qb + wave * 32 + tt * 16 + l16) * QKD;
#pragma unroll
    for (int c = 0; c < 6; ++c) aq[tt][c] = *(const bf16x8*)(qbase + c * 32 + quad * 8);
  }

  f32x4 o[2][8] = {};           // O^T: rows d (8 tiles), cols t (l16); [tt]
  float m_i[2] = {-3.0e38f, -3.0e38f}, l_i[2] = {0.f, 0.f};

  const bf16_t* kg_base = Kp + (size_t)h * T_DIM * QKD;
  const bf16_t* vg_base = VT + (size_t)(h * HS) * T_DIM;

  // register prefetch (6 K-chunks + 4 V-chunks per thread, 256 threads)
  bf16x8 kreg[6], vreg[4];
  {
    const bf16_t* kg = kg_base + (size_t)kt0 * FBN * QKD;
#pragma unroll
    for (int i = 0; i < 6; ++i) {
      int idx = i * 256 + tid;  // 64 rows * 24 vec8
      kreg[i] = *(const bf16x8*)(kg + (size_t)idx * 8);
    }
    const bf16_t* vg = vg_base + kt0 * FBN;
#pragma unroll
    for (int i = 0; i < 4; ++i) {
      int idx = i * 256 + tid, row = idx >> 3, c8 = idx & 7;
      vreg[i] = *(const bf16x8*)(vg + (size_t)row * T_DIM + c8 * 8);
    }
  }

  for (int kt = kt0; kt < kt1; ++kt) {
    __syncthreads();  // previous compute done -> LDS writable
#pragma unroll
    for (int i = 0; i < 6; ++i) {
      int idx = i * 256 + tid, row = idx / 24, c8 = idx % 24;
      *(bf16x8*)(Ksm + row * KPITCH + c8 * 8) = kreg[i];
    }
#pragma unroll
    for (int i = 0; i < 4; ++i) {
      int idx = i * 256 + tid, row = idx >> 3, c8 = idx & 7;
      *(bf16x8*)(Vtsm + row * VPITCH + c8 * 8) = vreg[i];
    }
    __syncthreads();  // LDS ready
    if (kt + 1 < kt1) {
      const bf16_t* kg = kg_base + (size_t)(kt + 1) * FBN * QKD;
#pragma unroll
      for (int i = 0; i < 6; ++i) {
        int idx = i * 256 + tid;
        kreg[i] = *(const bf16x8*)(kg + (size_t)idx * 8);
      }
      const bf16_t* vg = vg_base + (kt + 1) * FBN;
#pragma unroll
      for (int i = 0; i < 4; ++i) {
        int idx = i * 256 + tid, row = idx >> 3, c8 = idx & 7;
        vreg[i] = *(const bf16x8*)(vg + (size_t)row * T_DIM + c8 * 8);
      }
    }
    // S^T = K @ Q^T : rows s (4 tiles of 16), cols t (2 tiles, l16)
    f32x4 sc[2][4] = {};
    __builtin_amdgcn_s_setprio(1);
#pragma unroll
    for (int nt = 0; nt < 4; ++nt)
#pragma unroll
      for (int c = 0; c < 6; ++c) {
        bf16x8 bk = *(const bf16x8*)(Ksm + (nt * 16 + l16) * KPITCH + c * 32 + quad * 8);
        sc[0][nt] = __builtin_amdgcn_mfma_f32_16x16x32_bf16(bk, aq[0][c], sc[0][nt], 0, 0, 0);
        sc[1][nt] = __builtin_amdgcn_mfma_f32_16x16x32_bf16(bk, aq[1][c], sc[1][nt], 0, 0, 0);
      }
    __builtin_amdgcn_s_setprio(0);
    if (kt >= 2 * qt) {  // diagonal region
#pragma unroll
      for (int tt = 0; tt < 2; ++tt) {
        int t_glob = qb + wave * 32 + tt * 16 + l16;
#pragma unroll
        for (int nt = 0; nt < 4; ++nt) {
          int s_base = kt * FBN + nt * 16 + quad * 4;
#pragma unroll
          for (int r = 0; r < 4; ++r)
            if (s_base + r > t_glob) sc[tt][nt][r] = -3.0e38f;
        }
      }
    }
    // online softmax per t-column (l16); defer-max (T13); P packed in-register
    unsigned int pk32[2][4][2];
#pragma unroll
    for (int tt = 0; tt < 2; ++tt) {
      float mx = sc[tt][0][0];
#pragma unroll
      for (int nt = 0; nt < 4; ++nt)
#pragma unroll
        for (int r = 0; r < 4; ++r) mx = fmaxf(mx, sc[tt][nt][r]);
      mx = fmaxf(mx, __shfl_xor(mx, 16, 64));
      mx = fmaxf(mx, __shfl_xor(mx, 32, 64));
      int need = (mx > m_i[tt] + 5.5f) ? 1 : 0;
      if (__any(need)) {
        float mn = fmaxf(m_i[tt], mx);
        float alpha = fexp2((m_i[tt] - mn) * L2E);
        m_i[tt] = mn;
        l_i[tt] *= alpha;
#pragma unroll
        for (int dt = 0; dt < 8; ++dt) o[tt][dt] *= alpha;
      }
      float rs = 0.f;
#pragma unroll
      for (int nt = 0; nt < 4; ++nt) {
        float p0 = fexp2((sc[tt][nt][0] - m_i[tt]) * L2E);
        float p1 = fexp2((sc[tt][nt][1] - m_i[tt]) * L2E);
        float p2 = fexp2((sc[tt][nt][2] - m_i[tt]) * L2E);
        float p3 = fexp2((sc[tt][nt][3] - m_i[tt]) * L2E);
        rs += (p0 + p1) + (p2 + p3);
        asm("v_cvt_pk_bf16_f32 %0, %1, %2" : "=v"(pk32[tt][nt][0]) : "v"(p0), "v"(p1));
        asm("v_cvt_pk_bf16_f32 %0, %1, %2" : "=v"(pk32[tt][nt][1]) : "v"(p2), "v"(p3));
      }
      rs += __shfl_xor(rs, 16, 64);
      rs += __shfl_xor(rs, 32, 64);
      l_i[tt] += rs;
    }
    // O^T += V^T @ P^T; P B-fragments assembled in-register via shfl.
    __builtin_amdgcn_s_setprio(1);
#pragma unroll
    for (int s2 = 0; s2 < 2; ++s2) {
      u32x4 wa, wb;
#pragma unroll
      for (int c = 0; c < 2; ++c) {
        unsigned int a0 = (unsigned int)__shfl((int)pk32[0][2 * s2][c], srcA, 64);
        unsigned int a1 = (unsigned int)__shfl((int)pk32[0][2 * s2 + 1][c], srcA, 64);
        wa[c] = hi ? a1 : a0;
        unsigned int a2 = (unsigned int)__shfl((int)pk32[0][2 * s2][c], srcB, 64);
        unsigned int a3 = (unsigned int)__shfl((int)pk32[0][2 * s2 + 1][c], srcB, 64);
        wa[2 + c] = hi ? a3 : a2;
        unsigned int b0 = (unsigned int)__shfl((int)pk32[1][2 * s2][c], srcA, 64);
        unsigned int b1 = (unsigned int)__shfl((int)pk32[1][2 * s2 + 1][c], srcA, 64);
        wb[c] = hi ? b1 : b0;
        unsigned int b2 = (unsigned int)__shfl((int)pk32[1][2 * s2][c], srcB, 64);
        unsigned int b3 = (unsigned int)__shfl((int)pk32[1][2 * s2 + 1][c], srcB, 64);
        wb[2 + c] = hi ? b3 : b2;
      }
      bf16x8 ap0 = __builtin_bit_cast(bf16x8, wa);
      bf16x8 ap1 = __builtin_bit_cast(bf16x8, wb);
#pragma unroll
      for (int dt = 0; dt < 8; ++dt) {
        bf16x8 bv = *(const bf16x8*)(Vtsm + (dt * 16 + l16) * VPITCH + s2 * 32 + quad * 8);
        o[0][dt] = __builtin_amdgcn_mfma_f32_16x16x32_bf16(bv, ap0, o[0][dt], 0, 0, 0);
        o[1][dt] = __builtin_amdgcn_mfma_f32_16x16x32_bf16(bv, ap1, o[1][dt], 0, 0, 0);
      }
    }
    __builtin_amdgcn_s_setprio(0);
  }

  if (!partial) {
#pragma unroll
    for (int tt = 0; tt < 2; ++tt) {
      float inv = 1.0f / l_i[tt];
      int t = qb + wave * 32 + tt * 16 + l16;
#pragma unroll
      for (int dt = 0; dt < 8; ++dt) {
        size_t oi = (size_t)t * C_DIM + h * HS + dt * 16 + quad * 4;
        if (f32out) {
          f32x4 v;
#pragma unroll
          for (int r = 0; r < 4; ++r) v[r] = o[tt][dt][r] * inv;
          *(f32x4*)((float*)Y + oi) = v;
        } else {
          bf16x4 v;
#pragma unroll
          for (int r = 0; r < 4; ++r) v[r] = (bf16_t)(o[tt][dt][r] * inv);
          *(bf16x4*)((bf16_t*)Y + oi) = v;
        }
      }
    }
  } else {
    const int pi = h * 24 + c_pbase[qt] + part;
    float* obase = opart_at(OpartA, OpartB, pi);
#pragma unroll
    for (int tt = 0; tt < 2; ++tt) {
      int rowl = wave * 32 + tt * 16 + l16;  // 0..127
      float* ob = obase + (size_t)rowl * 128;
#pragma unroll
      for (int dt = 0; dt < 8; ++dt) {
        f32x4 v = o[tt][dt];
        *(f32x4*)(ob + dt * 16 + quad * 4) = v;
      }
      if (quad == 0) {
        Mpart[(size_t)pi * 128 + rowl] = m_i[tt];
        Lpart[(size_t)pi * 128 + rowl] = l_i[tt];
      }
    }
  }
}

// ---------------------------------------------------------------- combine partials (qt>=6)
__global__ __launch_bounds__(256) void combine_k(const float* __restrict__ OpartA,
                                                 const float* __restrict__ OpartB,
                                                 const float* __restrict__ Mpart,
                                                 const float* __restrict__ Lpart,
                                                 void* __restrict__ Y,
                                                 const bf16_t* __restrict__ xprobe) {
  const int h = blockIdx.y;
  const int qt = 6 + blockIdx.x;       // 6..15
  const int c = (qt <= 11) ? 2 : 3;
  const int pib = h * 24 + c_pbase[qt];
  const int row = threadIdx.x >> 1;    // 0..127
  const int c0 = (threadIdx.x & 1) * 64;
  const int f32out = probe_f32(xprobe);
  const float L2E = 1.4426950408889634f;
  float m0 = Mpart[(size_t)pib * 128 + row];
  float m1 = Mpart[(size_t)(pib + 1) * 128 + row];
  float l0 = Lpart[(size_t)pib * 128 + row];
  float l1 = Lpart[(size_t)(pib + 1) * 128 + row];
  float m2 = -3.0e38f, l2 = 0.f;
  if (c == 3) {
    m2 = Mpart[(size_t)(pib + 2) * 128 + row];
    l2 = Lpart[(size_t)(pib + 2) * 128 + row];
  }
  float ms = fmaxf(m0, fmaxf(m1, m2));
  float w0 = fexp2((m0 - ms) * L2E);
  float w1 = fexp2((m1 - ms) * L2E);
  float w2 = fexp2((m2 - ms) * L2E);
  float inv = 1.0f / (l0 * w0 + l1 * w1 + l2 * w2);
  const float* O0 = opart_atc(OpartA, OpartB, pib) + (size_t)row * 128 + c0;
  const float* O1 = opart_atc(OpartA, OpartB, pib + 1) + (size_t)row * 128 + c0;
  const float* O2 = opart_atc(OpartA, OpartB, pib + 2) + (size_t)row * 128 + c0;
  int t = qt * 128 + row;
  size_t ob = (size_t)t * C_DIM + h * HS + c0;
#pragma unroll
  for (int d4 = 0; d4 < 64; d4 += 4) {
    f32x4 a = *(const f32x4*)(O0 + d4);
    f32x4 b = *(const f32x4*)(O1 + d4);
    f32x4 acc;
#pragma unroll
    for (int j = 0; j < 4; ++j) acc[j] = a[j] * w0 + b[j] * w1;
    if (c == 3) {
      f32x4 e = *(const f32x4*)(O2 + d4);
#pragma unroll
      for (int j = 0; j < 4; ++j) acc[j] += e[j] * w2;
    }
#pragma unroll
    for (int j = 0; j < 4; ++j) {
      float v = acc[j] * inv;
      if (f32out) ((float*)Y)[ob + d4 + j] = v;
      else        ((bf16_t*)Y)[ob + d4 + j] = (bf16_t)v;
    }
  }
}

// ---------------------------------------------------------------- launch
extern "C" void kernel_launch(void* const* d_in, const int* in_sizes, int n_in,
                              void* d_out, int out_size, void* d_ws, size_t ws_size,
                              hipStream_t stream) {
  bf16_t* w = (bf16_t*)d_ws;
  const bf16_t* xprobe = (const bf16_t*)d_in[0];

  if (ws_size < (size_t)34472000 * 2 + 128) return;

  // ---- workspace layout (bf16 elements), lifetime-aliased ----
  bf16_t* fcc    = w + 64;        // 65536
  bf16_t* fsc    = w + 65600;     // 65536
  bf16_t* xc     = w + 131136;    // 4194304
  bf16_t* BigB   = w + 4325440;   // 4325376 = [W_dq(1536) | W_dkv(512) | W_kr(64)] x 2048
  bf16_t* dqc    = BigB;
  bf16_t* dkvc   = BigB + 3145728;
  bf16_t* krc    = BigB + 4194304;
  bf16_t* Bq     = w + 8650816;   // 4718592 = [W_uq_t(2048) | W_qr(1024)] x 1536
  bf16_t* W_uq_t = Bq;
  bf16_t* qrc    = Bq + 3145728;
  bf16_t* xa     = w + 13369408;  // 4325376: cols [c_q(1536) | c_kv(512) | k_r(64)], ld 2112
  bf16_t* qcat   = w + 17694784;  // 6291456: cols [q_up(2048) | q_r(1024)], ld 3072
  bf16_t* k_head = w + 23986240;  // 4194304
  bf16_t* vhatT  = w + 28180544;  // 4194304
  bf16_t* ukc    = w + 32374848;  // 1048576
  bf16_t* Pt     = w + 33423424;  // 1048576
  // aliases (lifetime-disjoint)
  bf16_t* woc    = qcat;          // dead before qcat GEMM writes here
  bf16_t* W_uv_t = k_head;        // dead before k_head GEMM writes here
  bf16_t* Qpack  = xc;            // xc + BigB head; ends at elem 6422592
  bf16_t* Kpack  = qcat;          // qcat dead after pack
  // flash partials, 384 slots of 128x128 f32, split across two dead regions:
  //   region A [6422592, 17694784): slots 0..337 + Mpart/Lpart at the tail
  //   region B [23986240, 28180544) (dead k_head): slots 338..383
  float* OpartA = (float*)(w + 6422592);   // 338 slots: ends at elem 17498176
  float* Mpart  = (float*)(w + 17498176);  // 384*128 f32 -> ends 17596480
  float* Lpart  = (float*)(w + 17596480);  // -> ends 17694784 (= qcat start)
  float* OpartB = (float*)(w + 23986240);  // 46 slots: ends at elem 25493568

  // prep: 9 converts + 2 transposes, one launch
  PrepPack pp;
  const void* srcs[9] = {d_in[1], d_in[2], d_in[0], d_in[3], d_in[5], d_in[9], d_in[8], d_in[6], d_in[10]};
  bf16_t* dsts[9]     = {fcc,     fsc,     xc,      dqc,     dkvc,    krc,     qrc,     ukc,     woc};
  int ns[9] = {T_DIM * 32, T_DIM * 32, T_DIM * C_DIM, NLQ * C_DIM, NLKV * C_DIM,
               DHR * C_DIM, NH * DHR * NLQ, C_DIM * NLKV, C_DIM * C_DIM};
  for (int i = 0; i < 9; ++i) { pp.src[i] = srcs[i]; pp.dst[i] = dsts[i]; pp.n[i] = ns[i]; }
  pp.tsrc[0] = d_in[4]; pp.tdst[0] = W_uq_t; pp.tR[0] = 1536; pp.tC[0] = 2048; pp.tbx[0] = 64;
  pp.tsrc[1] = d_in[7]; pp.tdst[1] = W_uv_t; pp.tR[1] = 2048; pp.tC[1] = 512;  pp.tbx[1] = 16;
  prep_k<<<dim3(3072, 11), 256, 0, stream>>>(pp, xprobe);

  // G1: xa (272 blk) || Pt (64 blk)
  {
    GGrp g;
    g.d[0] = {xc,  BigB,   xa, 2048, 2112, 2048, 2048, 2048, 2112, 16, 0};
    g.d[1] = {woc, W_uv_t, Pt, 2048,  512, 2048, 2048, 2048,  512, 16, 272};
    gemm_group<<<336, 256, 0, stream>>>(g, 2);
  }
  // G2: qcat (384) || k_head (256) || vhatT (256)
  {
    GGrp g;
    g.d[0] = {xa,        Bq,        qcat,   2048, 3072, 1536, 2112, 1536, 3072, 16, 0};
    g.d[1] = {xa + 1536, ukc,       k_head, 2048, 2048,  512, 2112,  512, 2048, 16, 384};
    g.d[2] = {Pt,        xa + 1536, vhatT,  2048, 2048,  512,  512, 2112, 2048, 16, 640};
    gemm_group<<<896, 256, 0, stream>>>(g, 3);
  }

  int pk = (NH * T_DIM * 96 + 255) / 256;
  pack_qk_k<<<dim3(pk, 2), 256, 0, stream>>>(qcat, k_head, xa, fcc, fsc, Qpack, Kpack);

  flash_k<<<dim3(480), 256, 0, stream>>>(Qpack, Kpack, vhatT, d_out, xprobe,
                                         OpartA, OpartB, Mpart, Lpart);
  combine_k<<<dim3(10, NH), 256, 0, stream>>>(OpartA, OpartB, Mpart, Lpart, d_out, xprobe);
}

// Round 7
// 306.456 us; speedup vs baseline: 1.3409x; 1.0418x over previous
//
#include <hip/hip_runtime.h>
#include <hip/hip_bf16.h>
#include <math.h>

typedef __bf16 bf16_t;
typedef __bf16 bf16x4 __attribute__((ext_vector_type(4)));
typedef __bf16 bf16x8 __attribute__((ext_vector_type(8)));
typedef float f32x4 __attribute__((ext_vector_type(4)));

#define T_DIM 2048
#define C_DIM 2048
#define NH 16
#define HS 128
#define NLQ 1536
#define NLKV 512
#define DHR 64
#define QKD 192  // HS + DHR

// flash work decomposition: per (head, qt) the 2qt+2 KV tiles are split into
// 1/2/3 balanced chunks (max span 12); slots ordered longest-first.
__constant__ int c_qt_tab[30] = {5,11,11,15,15,10,10,15,14,14,14,9,9,13,4,
                                 13,13,8,8,12,12,12,3,7,7,6,6,2,1,0};
__constant__ int c_pt_tab[30] = {0,0,1,0,1,0,1,2,0,1,2,0,1,0,0,
                                 1,2,0,1,0,1,2,0,0,1,0,1,0,0,0};
__constant__ int c_pbase[16]  = {0,0,0,0,0,0,0,2,4,6,8,10,12,15,18,21};

#define NSLOT_A 338  // Opart slots in region A; rest in region B

// inline dtype probe: true (f32 inputs) iff reading x as bf16 yields huge/NaN.
__device__ __forceinline__ int probe_f32(const bf16_t* __restrict__ x) {
  int lane = threadIdx.x & 63;
  int bad = 0;
#pragma unroll
  for (int i = 0; i < 4; ++i) {
    float v = (float)x[lane + i * 64];
    if (!(fabsf(v) < 1.0e6f)) bad = 1;
  }
  return (__ballot(bad) != 0ull) ? 1 : 0;
}

__device__ __forceinline__ float* opart_at(float* A, float* B, int pi) {
  return (pi < NSLOT_A) ? (A + (size_t)pi * 16384) : (B + (size_t)(pi - NSLOT_A) * 16384);
}
__device__ __forceinline__ const float* opart_atc(const float* A, const float* B, int pi) {
  return (pi < NSLOT_A) ? (A + (size_t)pi * 16384) : (B + (size_t)(pi - NSLOT_A) * 16384);
}

// ---------------------------------------------------------------- prep: 9 converts + 2 transposes
struct PrepPack {
  const void* src[9];
  bf16_t* dst[9];
  int n[9];
  const void* tsrc[2];
  bf16_t* tdst[2];
  int tR[2], tC[2], tbx[2];  // in R x C -> out C x R; tbx = C/32
};

__global__ __launch_bounds__(256) void prep_k(PrepPack p, const bf16_t* __restrict__ xprobe) {
  __shared__ bf16_t tile[32][33];
  const int f32 = probe_f32(xprobe);
  const int which = blockIdx.y;
  if (which < 9) {
    const int n = p.n[which];
    const int stride = gridDim.x * 256 * 8;
    for (int i = (blockIdx.x * 256 + threadIdx.x) * 8; i < n; i += stride) {
      if (f32) {
        const float* s = (const float*)p.src[which] + i;
        f32x4 lo = *(const f32x4*)s;
        f32x4 hi = *(const f32x4*)(s + 4);
        bf16x8 v;
#pragma unroll
        for (int j = 0; j < 4; ++j) { v[j] = (bf16_t)lo[j]; v[j + 4] = (bf16_t)hi[j]; }
        *(bf16x8*)(p.dst[which] + i) = v;
      } else {
        *(bf16x8*)(p.dst[which] + i) = *(const bf16x8*)((const bf16_t*)p.src[which] + i);
      }
    }
  } else {
    const int ts = which - 9;
    const int R = p.tR[ts], C = p.tC[ts], tbx = p.tbx[ts];
    const int ntiles = tbx * (R / 32);
    if ((int)blockIdx.x >= ntiles) return;
    const void* in = p.tsrc[ts];
    bf16_t* out = p.tdst[ts];
    int bx = (blockIdx.x % tbx) * 32, by = (blockIdx.x / tbx) * 32;
    int tx = threadIdx.x & 31, ty = threadIdx.x >> 5;  // 32 x 8
    for (int i = ty; i < 32; i += 8) {
      int r = by + i, c = bx + tx;
      size_t idx = (size_t)r * C + c;
      tile[i][tx] = f32 ? (bf16_t)((const float*)in)[idx] : ((const bf16_t*)in)[idx];
    }
    __syncthreads();
    for (int i = ty; i < 32; i += 8) {
      int r = bx + i, c = by + tx;  // out[r][c] = in[c][r]
      out[(size_t)r * R + c] = tile[tx][i];
    }
  }
}

// ---------------------------------------------------------------- async global->LDS (16B)
__device__ __forceinline__ void async16(const bf16_t* g, bf16_t* l) {
  __builtin_amdgcn_global_load_lds(
      (const __attribute__((address_space(1))) void*)g,
      (__attribute__((address_space(3))) void*)l, 16, 0, 0);
}

__device__ __forceinline__ float fexp2(float x) {
  return __builtin_amdgcn_exp2f(x);
}

// ---------------------------------------------------------------- grouped GEMM  C = A @ B^T
// 2-phase double-buffered pipeline (T3 minimum template), BK=64, XOR-swizzled LDS.
#define BM 128
#define BN 128
#define BKG 64

struct GDesc {
  const bf16_t* A; const bf16_t* B; bf16_t* C;
  int M, N, K, lda, ldb, ldc, mb, bx0;
};
struct GGrp { GDesc d[3]; };

__global__ __launch_bounds__(256) void gemm_group(GGrp g, int nseg) {
  int bx = blockIdx.x;
  int s = 0;
  while (s + 1 < nseg && bx >= g.d[s + 1].bx0) ++s;
  const GDesc D = g.d[s];
  const int local = bx - D.bx0;
  const int bm = (local % D.mb) * BM, bn = (local / D.mb) * BN;

  __shared__ bf16_t As[2][BM * BKG];  // 16 KB x2
  __shared__ bf16_t Bs[2][BN * BKG];  // 16 KB x2  (total 64 KB -> 2 blocks/CU)
  const int tid = threadIdx.x;
  const int lane = tid & 63;
  const int wave = tid >> 6;
  const int l16 = lane & 15, quad = lane >> 4;
  const int wm = (wave >> 1) * 64, wn = (wave & 1) * 64;
  f32x4 acc[4][4] = {};

  const int nt = D.K / BKG;

  // prologue: stage tile 0 into buffer 0
#pragma unroll
  for (int r = 0; r < 4; ++r) {
    int c = r * 256 + tid;           // 16B chunk 0..1023, row-major [128][8]
    int row = c >> 3;
    int c8 = (c & 7) ^ (row & 7);    // inverse swizzle on the global source
    int ar = bm + row; if (ar > D.M - 1) ar = D.M - 1;
    int br = bn + row; if (br > D.N - 1) br = D.N - 1;
    async16(D.A + (size_t)ar * D.lda + c8 * 8, &As[0][c * 8]);
    async16(D.B + (size_t)br * D.ldb + c8 * 8, &Bs[0][c * 8]);
  }
  asm volatile("s_waitcnt vmcnt(0)" ::: "memory");
  __builtin_amdgcn_s_barrier();

  for (int t = 0; t < nt; ++t) {
    const int cur = t & 1;
    if (t + 1 < nt) {
      const int k0 = (t + 1) * BKG;
#pragma unroll
      for (int r = 0; r < 4; ++r) {
        int c = r * 256 + tid;
        int row = c >> 3;
        int c8 = (c & 7) ^ (row & 7);
        int ar = bm + row; if (ar > D.M - 1) ar = D.M - 1;
        int br = bn + row; if (br > D.N - 1) br = D.N - 1;
        async16(D.A + (size_t)ar * D.lda + k0 + c8 * 8, &As[cur ^ 1][c * 8]);
        async16(D.B + (size_t)br * D.ldb + k0 + c8 * 8, &Bs[cur ^ 1][c * 8]);
      }
    }
#pragma unroll
    for (int kk = 0; kk < 2; ++kk) {
      bf16x8 af[4], bfr[4];
#pragma unroll
      for (int i = 0; i < 4; ++i) {
        int row = wm + i * 16 + l16;
        af[i] = *(const bf16x8*)(&As[cur][row * BKG + (((kk * 4 + quad) ^ (row & 7)) * 8)]);
      }
#pragma unroll
      for (int j = 0; j < 4; ++j) {
        int row = wn + j * 16 + l16;
        bfr[j] = *(const bf16x8*)(&Bs[cur][row * BKG + (((kk * 4 + quad) ^ (row & 7)) * 8)]);
      }
#pragma unroll
      for (int i = 0; i < 4; ++i)
#pragma unroll
        for (int j = 0; j < 4; ++j)
          acc[i][j] = __builtin_amdgcn_mfma_f32_16x16x32_bf16(af[i], bfr[j], acc[i][j], 0, 0, 0);
    }
    asm volatile("s_waitcnt vmcnt(0)" ::: "memory");
    __builtin_amdgcn_s_barrier();
  }

#pragma unroll
  for (int i = 0; i < 4; ++i)
#pragma unroll
    for (int j = 0; j < 4; ++j)
#pragma unroll
      for (int r = 0; r < 4; ++r) {
        int gm = bm + wm + i * 16 + quad * 4 + r;
        int gn = bn + wn + j * 16 + l16;
        if (gm < D.M && gn < D.N) D.C[(size_t)gm * D.ldc + gn] = (bf16_t)acc[i][j][r];
      }
}

// ---------------------------------------------------------------- fused pack + rope (vectorized, bf16x8)
__global__ __launch_bounds__(256) void pack_qk_k(const bf16_t* __restrict__ qcat,
                                                 const bf16_t* __restrict__ khead,
                                                 const bf16_t* __restrict__ xa,
                                                 const bf16_t* __restrict__ fc,
                                                 const bf16_t* __restrict__ fs,
                                                 bf16_t* __restrict__ Qp, bf16_t* __restrict__ Kp) {
  int idx = blockIdx.x * 256 + threadIdx.x;
  if (idx >= NH * T_DIM * 24) return;
  int j8 = idx % 24;                 // 24 x 8 elems = 192 per output row
  int t = (idx / 24) % T_DIM;
  int h = idx / (24 * T_DIM);
  if (blockIdx.y == 0) {
    const float scale = 0.07216878364870323f;  // 1/sqrt(HS+DHR)
    bf16_t* out = Qp + ((size_t)h * T_DIM + t) * QKD + j8 * 8;
    if (j8 < 16) {
      bf16x8 v = *(const bf16x8*)(qcat + (size_t)t * 3072 + h * HS + j8 * 8);
      bf16x8 r;
#pragma unroll
      for (int k = 0; k < 8; ++k) r[k] = (bf16_t)((float)v[k] * scale);
      *(bf16x8*)out = r;
    } else {
      int i0 = (j8 - 16) * 4;        // 4 rope pairs
      bf16x8 v = *(const bf16x8*)(qcat + (size_t)t * 3072 + 2048 + h * DHR + i0 * 2);
      bf16x4 cc = *(const bf16x4*)(fc + t * 32 + i0);
      bf16x4 ss = *(const bf16x4*)(fs + t * 32 + i0);
      bf16x8 r;
#pragma unroll
      for (int k = 0; k < 4; ++k) {
        float re = (float)v[2 * k], im = (float)v[2 * k + 1];
        float c = (float)cc[k], s = (float)ss[k];
        r[2 * k] = (bf16_t)((re * c - im * s) * scale);
        r[2 * k + 1] = (bf16_t)((re * s + im * c) * scale);
      }
      *(bf16x8*)out = r;
    }
  } else {
    bf16_t* out = Kp + ((size_t)h * T_DIM + t) * QKD + j8 * 8;
    if (j8 < 16) {
      *(bf16x8*)out = *(const bf16x8*)(khead + (size_t)t * C_DIM + h * HS + j8 * 8);
    } else {
      int i0 = (j8 - 16) * 4;
      bf16x8 v = *(const bf16x8*)(xa + (size_t)t * 2112 + 2048 + i0 * 2);
      bf16x4 cc = *(const bf16x4*)(fc + t * 32 + i0);
      bf16x4 ss = *(const bf16x4*)(fs + t * 32 + i0);
      bf16x8 r;
#pragma unroll
      for (int k = 0; k < 4; ++k) {
        float re = (float)v[2 * k], im = (float)v[2 * k + 1];
        float c = (float)cc[k], s = (float)ss[k];
        r[2 * k] = (bf16_t)(re * c - im * s);
        r[2 * k + 1] = (bf16_t)(re * s + im * c);
      }
      *(bf16x8*)out = r;
    }
  }
}

// ---------------------------------------------------------------- flash attention
// Round-3 verified structure (62.3 us): S^T orientation, 4 waves x 32 t-rows,
// FBM=128, FBN=64, balanced KV-split (<=12 tiles), reg-staged double-buffer,
// Psm per-wave staging; + setprio around MFMA clusters (T5).
#define FBM 128
#define FBN 64
#define KPITCH 200
#define VPITCH 72
#define PPITCH 72

__global__ __launch_bounds__(256) void flash_k(const bf16_t* __restrict__ Qp,
                                               const bf16_t* __restrict__ Kp,
                                               const bf16_t* __restrict__ VT,
                                               void* __restrict__ Y,
                                               const bf16_t* __restrict__ xprobe,
                                               float* __restrict__ OpartA,
                                               float* __restrict__ OpartB,
                                               float* __restrict__ Mpart,
                                               float* __restrict__ Lpart) {
  __shared__ bf16_t Ksm[FBN * KPITCH];    // 25.6 KB
  __shared__ bf16_t Vtsm[HS * VPITCH];    // 18.4 KB
  __shared__ bf16_t Psm[4][32 * PPITCH];  // 18.4 KB
  const int tid = threadIdx.x;
  const int lane = tid & 63, wave = tid >> 6;  // wave 0..3, 32 t-rows each
  const int l16 = lane & 15, quad = lane >> 4;
  const int id = blockIdx.x;
  const int xcd = id & 7, slot = id >> 3;
  const int h = xcd + 8 * (slot / 30);
  const int p = slot % 30;
  const int qt = c_qt_tab[p];
  const int part = c_pt_tab[p];
  const int nkv = 2 * qt + 2;
  const int nparts = (qt <= 5) ? 1 : (qt <= 11 ? 2 : 3);
  const int bse = nkv / nparts, rem = nkv % nparts;
  const int kt0 = part * bse + (part < rem ? part : rem);
  const int kt1 = kt0 + bse + (part < rem ? 1 : 0);
  const int partial = (nparts > 1);
  const int qb = qt * FBM;
  const int f32out = probe_f32(xprobe);
  const float L2E = 1.4426950408889634f;

  // Q fragments: two 16-row t-tiles per wave (B-operand: n=l16 rows)
  bf16x8 aq[2][6];
#pragma unroll
  for (int tt = 0; tt < 2; ++tt) {
    const bf16_t* qbase = Qp + ((size_t)h * T_DIM + qb + wave * 32 + tt * 16 + l16) * QKD;
#pragma unroll
    for (int c = 0; c < 6; ++c) aq[tt][c] = *(const bf16x8*)(qbase + c * 32 + quad * 8);
  }

  f32x4 o[2][8] = {};           // O^T: rows d (8 tiles), cols t (l16); [tt]
  float m_i[2] = {-3.0e38f, -3.0e38f}, l_i[2] = {0.f, 0.f};

  const bf16_t* kg_base = Kp + (size_t)h * T_DIM * QKD;
  const bf16_t* vg_base = VT + (size_t)(h * HS) * T_DIM;

  // register prefetch (6 K-chunks + 4 V-chunks per thread, 256 threads)
  bf16x8 kreg[6], vreg[4];
  {
    const bf16_t* kg = kg_base + (size_t)kt0 * FBN * QKD;
#pragma unroll
    for (int i = 0; i < 6; ++i) {
      int idx = i * 256 + tid;  // 64 rows * 24 vec8
      kreg[i] = *(const bf16x8*)(kg + (size_t)idx * 8);
    }
    const bf16_t* vg = vg_base + kt0 * FBN;
#pragma unroll
    for (int i = 0; i < 4; ++i) {
      int idx = i * 256 + tid, row = idx >> 3, c8 = idx & 7;
      vreg[i] = *(const bf16x8*)(vg + (size_t)row * T_DIM + c8 * 8);
    }
  }

  for (int kt = kt0; kt < kt1; ++kt) {
    __syncthreads();  // previous compute done -> LDS writable
#pragma unroll
    for (int i = 0; i < 6; ++i) {
      int idx = i * 256 + tid, row = idx / 24, c8 = idx % 24;
      *(bf16x8*)(Ksm + row * KPITCH + c8 * 8) = kreg[i];
    }
#pragma unroll
    for (int i = 0; i < 4; ++i) {
      int idx = i * 256 + tid, row = idx >> 3, c8 = idx & 7;
      *(bf16x8*)(Vtsm + row * VPITCH + c8 * 8) = vreg[i];
    }
    __syncthreads();  // LDS ready
    if (kt + 1 < kt1) {
      const bf16_t* kg = kg_base + (size_t)(kt + 1) * FBN * QKD;
#pragma unroll
      for (int i = 0; i < 6; ++i) {
        int idx = i * 256 + tid;
        kreg[i] = *(const bf16x8*)(kg + (size_t)idx * 8);
      }
      const bf16_t* vg = vg_base + (kt + 1) * FBN;
#pragma unroll
      for (int i = 0; i < 4; ++i) {
        int idx = i * 256 + tid, row = idx >> 3, c8 = idx & 7;
        vreg[i] = *(const bf16x8*)(vg + (size_t)row * T_DIM + c8 * 8);
      }
    }
    // S^T = K @ Q^T : rows s (4 tiles of 16), cols t (2 tiles, l16)
    f32x4 sc[2][4] = {};
    __builtin_amdgcn_s_setprio(1);
#pragma unroll
    for (int nt = 0; nt < 4; ++nt)
#pragma unroll
      for (int c = 0; c < 6; ++c) {
        bf16x8 bk = *(const bf16x8*)(Ksm + (nt * 16 + l16) * KPITCH + c * 32 + quad * 8);
        sc[0][nt] = __builtin_amdgcn_mfma_f32_16x16x32_bf16(bk, aq[0][c], sc[0][nt], 0, 0, 0);
        sc[1][nt] = __builtin_amdgcn_mfma_f32_16x16x32_bf16(bk, aq[1][c], sc[1][nt], 0, 0, 0);
      }
    __builtin_amdgcn_s_setprio(0);
    if (kt >= 2 * qt) {  // diagonal region
#pragma unroll
      for (int tt = 0; tt < 2; ++tt) {
        int t_glob = qb + wave * 32 + tt * 16 + l16;
#pragma unroll
        for (int nt = 0; nt < 4; ++nt) {
          int s_base = kt * FBN + nt * 16 + quad * 4;
#pragma unroll
          for (int r = 0; r < 4; ++r)
            if (s_base + r > t_glob) sc[tt][nt][r] = -3.0e38f;
        }
      }
    }
    // online softmax per t-column (l16); defer-max (T13): skip rescale unless
    // the new tile max exceeds the running max by >5.5.
#pragma unroll
    for (int tt = 0; tt < 2; ++tt) {
      float mx = sc[tt][0][0];
#pragma unroll
      for (int nt = 0; nt < 4; ++nt)
#pragma unroll
        for (int r = 0; r < 4; ++r) mx = fmaxf(mx, sc[tt][nt][r]);
      mx = fmaxf(mx, __shfl_xor(mx, 16, 64));
      mx = fmaxf(mx, __shfl_xor(mx, 32, 64));
      int need = (mx > m_i[tt] + 5.5f) ? 1 : 0;
      if (__any(need)) {
        float mn = fmaxf(m_i[tt], mx);
        float alpha = fexp2((m_i[tt] - mn) * L2E);
        m_i[tt] = mn;
        l_i[tt] *= alpha;
#pragma unroll
        for (int dt = 0; dt < 8; ++dt) o[tt][dt] *= alpha;
      }
      float rs = 0.f;
#pragma unroll
      for (int nt = 0; nt < 4; ++nt) {
        float p0 = fexp2((sc[tt][nt][0] - m_i[tt]) * L2E);
        float p1 = fexp2((sc[tt][nt][1] - m_i[tt]) * L2E);
        float p2 = fexp2((sc[tt][nt][2] - m_i[tt]) * L2E);
        float p3 = fexp2((sc[tt][nt][3] - m_i[tt]) * L2E);
        rs += (p0 + p1) + (p2 + p3);
        uint2 pk;
        asm("v_cvt_pk_bf16_f32 %0, %1, %2" : "=v"(pk.x) : "v"(p0), "v"(p1));
        asm("v_cvt_pk_bf16_f32 %0, %1, %2" : "=v"(pk.y) : "v"(p2), "v"(p3));
        *(uint2*)(&Psm[wave][(tt * 16 + l16) * PPITCH + nt * 16 + quad * 4]) = pk;
      }
      rs += __shfl_xor(rs, 16, 64);
      rs += __shfl_xor(rs, 32, 64);
      l_i[tt] += rs;
    }
    // O^T += V^T @ P^T (per-wave Psm, no extra barrier)
    __builtin_amdgcn_s_setprio(1);
#pragma unroll
    for (int s2 = 0; s2 < 2; ++s2) {
      bf16x8 ap0 = *(const bf16x8*)(&Psm[wave][l16 * PPITCH + s2 * 32 + quad * 8]);
      bf16x8 ap1 = *(const bf16x8*)(&Psm[wave][(16 + l16) * PPITCH + s2 * 32 + quad * 8]);
#pragma unroll
      for (int dt = 0; dt < 8; ++dt) {
        bf16x8 bv = *(const bf16x8*)(Vtsm + (dt * 16 + l16) * VPITCH + s2 * 32 + quad * 8);
        o[0][dt] = __builtin_amdgcn_mfma_f32_16x16x32_bf16(bv, ap0, o[0][dt], 0, 0, 0);
        o[1][dt] = __builtin_amdgcn_mfma_f32_16x16x32_bf16(bv, ap1, o[1][dt], 0, 0, 0);
      }
    }
    __builtin_amdgcn_s_setprio(0);
  }

  if (!partial) {
#pragma unroll
    for (int tt = 0; tt < 2; ++tt) {
      float inv = 1.0f / l_i[tt];
      int t = qb + wave * 32 + tt * 16 + l16;
#pragma unroll
      for (int dt = 0; dt < 8; ++dt) {
        size_t oi = (size_t)t * C_DIM + h * HS + dt * 16 + quad * 4;
        if (f32out) {
          f32x4 v;
#pragma unroll
          for (int r = 0; r < 4; ++r) v[r] = o[tt][dt][r] * inv;
          *(f32x4*)((float*)Y + oi) = v;
        } else {
          bf16x4 v;
#pragma unroll
          for (int r = 0; r < 4; ++r) v[r] = (bf16_t)(o[tt][dt][r] * inv);
          *(bf16x4*)((bf16_t*)Y + oi) = v;
        }
      }
    }
  } else {
    const int pi = h * 24 + c_pbase[qt] + part;
    float* obase = opart_at(OpartA, OpartB, pi);
#pragma unroll
    for (int tt = 0; tt < 2; ++tt) {
      int rowl = wave * 32 + tt * 16 + l16;  // 0..127
      float* ob = obase + (size_t)rowl * 128;
#pragma unroll
      for (int dt = 0; dt < 8; ++dt) {
        f32x4 v = o[tt][dt];
        *(f32x4*)(ob + dt * 16 + quad * 4) = v;
      }
      if (quad == 0) {
        Mpart[(size_t)pi * 128 + rowl] = m_i[tt];
        Lpart[(size_t)pi * 128 + rowl] = l_i[tt];
      }
    }
  }
}

// ---------------------------------------------------------------- combine partials (qt>=6)
__global__ __launch_bounds__(256) void combine_k(const float* __restrict__ OpartA,
                                                 const float* __restrict__ OpartB,
                                                 const float* __restrict__ Mpart,
                                                 const float* __restrict__ Lpart,
                                                 void* __restrict__ Y,
                                                 const bf16_t* __restrict__ xprobe) {
  const int h = blockIdx.y;
  const int qt = 6 + blockIdx.x;       // 6..15
  const int c = (qt <= 11) ? 2 : 3;
  const int pib = h * 24 + c_pbase[qt];
  const int row = threadIdx.x >> 1;    // 0..127
  const int c0 = (threadIdx.x & 1) * 64;
  const int f32out = probe_f32(xprobe);
  const float L2E = 1.4426950408889634f;
  float m0 = Mpart[(size_t)pib * 128 + row];
  float m1 = Mpart[(size_t)(pib + 1) * 128 + row];
  float l0 = Lpart[(size_t)pib * 128 + row];
  float l1 = Lpart[(size_t)(pib + 1) * 128 + row];
  float m2 = -3.0e38f, l2 = 0.f;
  if (c == 3) {
    m2 = Mpart[(size_t)(pib + 2) * 128 + row];
    l2 = Lpart[(size_t)(pib + 2) * 128 + row];
  }
  float ms = fmaxf(m0, fmaxf(m1, m2));
  float w0 = fexp2((m0 - ms) * L2E);
  float w1 = fexp2((m1 - ms) * L2E);
  float w2 = fexp2((m2 - ms) * L2E);
  float inv = 1.0f / (l0 * w0 + l1 * w1 + l2 * w2);
  const float* O0 = opart_atc(OpartA, OpartB, pib) + (size_t)row * 128 + c0;
  const float* O1 = opart_atc(OpartA, OpartB, pib + 1) + (size_t)row * 128 + c0;
  const float* O2 = opart_atc(OpartA, OpartB, pib + 2) + (size_t)row * 128 + c0;
  int t = qt * 128 + row;
  size_t ob = (size_t)t * C_DIM + h * HS + c0;
#pragma unroll
  for (int d4 = 0; d4 < 64; d4 += 4) {
    f32x4 a = *(const f32x4*)(O0 + d4);
    f32x4 b = *(const f32x4*)(O1 + d4);
    f32x4 acc;
#pragma unroll
    for (int j = 0; j < 4; ++j) acc[j] = a[j] * w0 + b[j] * w1;
    if (c == 3) {
      f32x4 e = *(const f32x4*)(O2 + d4);
#pragma unroll
      for (int j = 0; j < 4; ++j) acc[j] += e[j] * w2;
    }
#pragma unroll
    for (int j = 0; j < 4; ++j) {
      float v = acc[j] * inv;
      if (f32out) ((float*)Y)[ob + d4 + j] = v;
      else        ((bf16_t*)Y)[ob + d4 + j] = (bf16_t)v;
    }
  }
}

// ---------------------------------------------------------------- launch
extern "C" void kernel_launch(void* const* d_in, const int* in_sizes, int n_in,
                              void* d_out, int out_size, void* d_ws, size_t ws_size,
                              hipStream_t stream) {
  bf16_t* w = (bf16_t*)d_ws;
  const bf16_t* xprobe = (const bf16_t*)d_in[0];

  if (ws_size < (size_t)34472000 * 2 + 128) return;

  // ---- workspace layout (bf16 elements), lifetime-aliased ----
  bf16_t* fcc    = w + 64;        // 65536
  bf16_t* fsc    = w + 65600;     // 65536
  bf16_t* xc     = w + 131136;    // 4194304
  bf16_t* BigB   = w + 4325440;   // 4325376 = [W_dq(1536) | W_dkv(512) | W_kr(64)] x 2048
  bf16_t* dqc    = BigB;
  bf16_t* dkvc   = BigB + 3145728;
  bf16_t* krc    = BigB + 4194304;
  bf16_t* Bq     = w + 8650816;   // 4718592 = [W_uq_t(2048) | W_qr(1024)] x 1536
  bf16_t* W_uq_t = Bq;
  bf16_t* qrc    = Bq + 3145728;
  bf16_t* xa     = w + 13369408;  // 4325376: cols [c_q(1536) | c_kv(512) | k_r(64)], ld 2112
  bf16_t* qcat   = w + 17694784;  // 6291456: cols [q_up(2048) | q_r(1024)], ld 3072
  bf16_t* k_head = w + 23986240;  // 4194304
  bf16_t* vhatT  = w + 28180544;  // 4194304
  bf16_t* ukc    = w + 32374848;  // 1048576
  bf16_t* Pt     = w + 33423424;  // 1048576
  // aliases (lifetime-disjoint)
  bf16_t* woc    = qcat;          // dead before qcat GEMM writes here
  bf16_t* W_uv_t = k_head;        // dead before k_head GEMM writes here
  bf16_t* Qpack  = xc;            // xc + BigB head; ends at elem 6422592
  bf16_t* Kpack  = qcat;          // qcat dead after pack
  // flash partials, 384 slots of 128x128 f32, split across two dead regions:
  //   region A [6422592, 17694784): slots 0..337 + Mpart/Lpart at the tail
  //   region B [23986240, 28180544) (dead k_head): slots 338..383
  float* OpartA = (float*)(w + 6422592);   // 338 slots: ends at elem 17498176
  float* Mpart  = (float*)(w + 17498176);  // 384*128 f32 -> ends 17596480
  float* Lpart  = (float*)(w + 17596480);  // -> ends 17694784 (= qcat start)
  float* OpartB = (float*)(w + 23986240);  // 46 slots: ends at elem 25493568

  // prep: 9 converts + 2 transposes, one launch
  PrepPack pp;
  const void* srcs[9] = {d_in[1], d_in[2], d_in[0], d_in[3], d_in[5], d_in[9], d_in[8], d_in[6], d_in[10]};
  bf16_t* dsts[9]     = {fcc,     fsc,     xc,      dqc,     dkvc,    krc,     qrc,     ukc,     woc};
  int ns[9] = {T_DIM * 32, T_DIM * 32, T_DIM * C_DIM, NLQ * C_DIM, NLKV * C_DIM,
               DHR * C_DIM, NH * DHR * NLQ, C_DIM * NLKV, C_DIM * C_DIM};
  for (int i = 0; i < 9; ++i) { pp.src[i] = srcs[i]; pp.dst[i] = dsts[i]; pp.n[i] = ns[i]; }
  pp.tsrc[0] = d_in[4]; pp.tdst[0] = W_uq_t; pp.tR[0] = 1536; pp.tC[0] = 2048; pp.tbx[0] = 64;
  pp.tsrc[1] = d_in[7]; pp.tdst[1] = W_uv_t; pp.tR[1] = 2048; pp.tC[1] = 512;  pp.tbx[1] = 16;
  prep_k<<<dim3(3072, 11), 256, 0, stream>>>(pp, xprobe);

  // G1: xa (272 blk) || Pt (64 blk)
  {
    GGrp g;
    g.d[0] = {xc,  BigB,   xa, 2048, 2112, 2048, 2048, 2048, 2112, 16, 0};
    g.d[1] = {woc, W_uv_t, Pt, 2048,  512, 2048, 2048, 2048,  512, 16, 272};
    gemm_group<<<336, 256, 0, stream>>>(g, 2);
  }
  // G2: qcat (384) || k_head (256) || vhatT (256)
  {
    GGrp g;
    g.d[0] = {xa,        Bq,        qcat,   2048, 3072, 1536, 2112, 1536, 3072, 16, 0};
    g.d[1] = {xa + 1536, ukc,       k_head, 2048, 2048,  512, 2112,  512, 2048, 16, 384};
    g.d[2] = {Pt,        xa + 1536, vhatT,  2048, 2048,  512,  512, 2112, 2048, 16, 640};
    gemm_group<<<896, 256, 0, stream>>>(g, 3);
  }

  pack_qk_k<<<dim3(3072, 2), 256, 0, stream>>>(qcat, k_head, xa, fcc, fsc, Qpack, Kpack);

  flash_k<<<dim3(480), 256, 0, stream>>>(Qpack, Kpack, vhatT, d_out, xprobe,
                                         OpartA, OpartB, Mpart, Lpart);
  combine_k<<<dim3(10, NH), 256, 0, stream>>>(OpartA, OpartB, Mpart, Lpart, d_out, xprobe);
}

// Round 9
// 305.713 us; speedup vs baseline: 1.3441x; 1.0024x over previous
//
#include <hip/hip_runtime.h>
#include <hip/hip_bf16.h>
#include <math.h>

typedef __bf16 bf16_t;
typedef __bf16 bf16x4 __attribute__((ext_vector_type(4)));
typedef __bf16 bf16x8 __attribute__((ext_vector_type(8)));
typedef float f32x4 __attribute__((ext_vector_type(4)));

#define T_DIM 2048
#define C_DIM 2048
#define NH 16
#define HS 128
#define NLQ 1536
#define NLKV 512
#define DHR 64
#define QKD 192  // HS + DHR

// flash work decomposition: per (head, qt) the 2qt+2 KV tiles are split into
// 1/2/3 balanced chunks (max span 12); slots ordered longest-first.
__constant__ int c_qt_tab[30] = {5,11,11,15,15,10,10,15,14,14,14,9,9,13,4,
                                 13,13,8,8,12,12,12,3,7,7,6,6,2,1,0};
__constant__ int c_pt_tab[30] = {0,0,1,0,1,0,1,2,0,1,2,0,1,0,0,
                                 1,2,0,1,0,1,2,0,0,1,0,1,0,0,0};
__constant__ int c_pbase[16]  = {0,0,0,0,0,0,0,2,4,6,8,10,12,15,18,21};

#define NSLOT_A 338  // Opart slots in region A; rest in region B

// inline dtype probe: true (f32 inputs) iff reading x as bf16 yields huge/NaN.
__device__ __forceinline__ int probe_f32(const bf16_t* __restrict__ x) {
  int lane = threadIdx.x & 63;
  int bad = 0;
#pragma unroll
  for (int i = 0; i < 4; ++i) {
    float v = (float)x[lane + i * 64];
    if (!(fabsf(v) < 1.0e6f)) bad = 1;
  }
  return (__ballot(bad) != 0ull) ? 1 : 0;
}

__device__ __forceinline__ float* opart_at(float* A, float* B, int pi) {
  return (pi < NSLOT_A) ? (A + (size_t)pi * 16384) : (B + (size_t)(pi - NSLOT_A) * 16384);
}
__device__ __forceinline__ const float* opart_atc(const float* A, const float* B, int pi) {
  return (pi < NSLOT_A) ? (A + (size_t)pi * 16384) : (B + (size_t)(pi - NSLOT_A) * 16384);
}

// ---------------------------------------------------------------- prep: 9 converts + 2 transposes
struct PrepPack {
  const void* src[9];
  bf16_t* dst[9];
  int n[9];
  const void* tsrc[2];
  bf16_t* tdst[2];
  int tR[2], tC[2], tbx[2];  // in R x C -> out C x R; tbx = C/32
};

__global__ __launch_bounds__(256) void prep_k(PrepPack p, const bf16_t* __restrict__ xprobe) {
  __shared__ bf16_t tile[32][33];
  const int f32 = probe_f32(xprobe);
  const int which = blockIdx.y;
  if (which < 9) {
    const int n = p.n[which];
    const int stride = gridDim.x * 256 * 8;
    for (int i = (blockIdx.x * 256 + threadIdx.x) * 8; i < n; i += stride) {
      if (f32) {
        const float* s = (const float*)p.src[which] + i;
        f32x4 lo = *(const f32x4*)s;
        f32x4 hi = *(const f32x4*)(s + 4);
        bf16x8 v;
#pragma unroll
        for (int j = 0; j < 4; ++j) { v[j] = (bf16_t)lo[j]; v[j + 4] = (bf16_t)hi[j]; }
        *(bf16x8*)(p.dst[which] + i) = v;
      } else {
        *(bf16x8*)(p.dst[which] + i) = *(const bf16x8*)((const bf16_t*)p.src[which] + i);
      }
    }
  } else {
    const int ts = which - 9;
    const int R = p.tR[ts], C = p.tC[ts], tbx = p.tbx[ts];
    const int ntiles = tbx * (R / 32);
    if ((int)blockIdx.x >= ntiles) return;
    const void* in = p.tsrc[ts];
    bf16_t* out = p.tdst[ts];
    int bx = (blockIdx.x % tbx) * 32, by = (blockIdx.x / tbx) * 32;
    int tx = threadIdx.x & 31, ty = threadIdx.x >> 5;  // 32 x 8
    for (int i = ty; i < 32; i += 8) {
      int r = by + i, c = bx + tx;
      size_t idx = (size_t)r * C + c;
      tile[i][tx] = f32 ? (bf16_t)((const float*)in)[idx] : ((const bf16_t*)in)[idx];
    }
    __syncthreads();
    for (int i = ty; i < 32; i += 8) {
      int r = bx + i, c = by + tx;  // out[r][c] = in[c][r]
      out[(size_t)r * R + c] = tile[tx][i];
    }
  }
}

// ---------------------------------------------------------------- async global->LDS (16B)
__device__ __forceinline__ void async16(const bf16_t* g, bf16_t* l) {
  __builtin_amdgcn_global_load_lds(
      (const __attribute__((address_space(1))) void*)g,
      (__attribute__((address_space(3))) void*)l, 16, 0, 0);
}

__device__ __forceinline__ float fexp2(float x) {
  return __builtin_amdgcn_exp2f(x);
}

// ---------------------------------------------------------------- grouped GEMM  C = A @ B^T
// 2-phase double-buffered pipeline (T3 minimum template), BK=64, XOR-swizzled LDS.
#define BM 128
#define BN 128
#define BKG 64

struct GDesc {
  const bf16_t* A; const bf16_t* B; bf16_t* C;
  int M, N, K, lda, ldb, ldc, mb, bx0;
};
struct GGrp { GDesc d[3]; };

__global__ __launch_bounds__(256) void gemm_group(GGrp g, int nseg) {
  int bx = blockIdx.x;
  int s = 0;
  while (s + 1 < nseg && bx >= g.d[s + 1].bx0) ++s;
  const GDesc D = g.d[s];
  const int local = bx - D.bx0;
  const int bm = (local % D.mb) * BM, bn = (local / D.mb) * BN;

  __shared__ bf16_t As[2][BM * BKG];  // 16 KB x2
  __shared__ bf16_t Bs[2][BN * BKG];  // 16 KB x2  (total 64 KB -> 2 blocks/CU)
  const int tid = threadIdx.x;
  const int lane = tid & 63;
  const int wave = tid >> 6;
  const int l16 = lane & 15, quad = lane >> 4;
  const int wm = (wave >> 1) * 64, wn = (wave & 1) * 64;
  f32x4 acc[4][4] = {};

  const int nt = D.K / BKG;

  // prologue: stage tile 0 into buffer 0
#pragma unroll
  for (int r = 0; r < 4; ++r) {
    int c = r * 256 + tid;           // 16B chunk 0..1023, row-major [128][8]
    int row = c >> 3;
    int c8 = (c & 7) ^ (row & 7);    // inverse swizzle on the global source
    int ar = bm + row; if (ar > D.M - 1) ar = D.M - 1;
    int br = bn + row; if (br > D.N - 1) br = D.N - 1;
    async16(D.A + (size_t)ar * D.lda + c8 * 8, &As[0][c * 8]);
    async16(D.B + (size_t)br * D.ldb + c8 * 8, &Bs[0][c * 8]);
  }
  asm volatile("s_waitcnt vmcnt(0)" ::: "memory");
  __builtin_amdgcn_s_barrier();

  for (int t = 0; t < nt; ++t) {
    const int cur = t & 1;
    if (t + 1 < nt) {
      const int k0 = (t + 1) * BKG;
#pragma unroll
      for (int r = 0; r < 4; ++r) {
        int c = r * 256 + tid;
        int row = c >> 3;
        int c8 = (c & 7) ^ (row & 7);
        int ar = bm + row; if (ar > D.M - 1) ar = D.M - 1;
        int br = bn + row; if (br > D.N - 1) br = D.N - 1;
        async16(D.A + (size_t)ar * D.lda + k0 + c8 * 8, &As[cur ^ 1][c * 8]);
        async16(D.B + (size_t)br * D.ldb + k0 + c8 * 8, &Bs[cur ^ 1][c * 8]);
      }
    }
#pragma unroll
    for (int kk = 0; kk < 2; ++kk) {
      bf16x8 af[4], bfr[4];
#pragma unroll
      for (int i = 0; i < 4; ++i) {
        int row = wm + i * 16 + l16;
        af[i] = *(const bf16x8*)(&As[cur][row * BKG + (((kk * 4 + quad) ^ (row & 7)) * 8)]);
      }
#pragma unroll
      for (int j = 0; j < 4; ++j) {
        int row = wn + j * 16 + l16;
        bfr[j] = *(const bf16x8*)(&Bs[cur][row * BKG + (((kk * 4 + quad) ^ (row & 7)) * 8)]);
      }
#pragma unroll
      for (int i = 0; i < 4; ++i)
#pragma unroll
        for (int j = 0; j < 4; ++j)
          acc[i][j] = __builtin_amdgcn_mfma_f32_16x16x32_bf16(af[i], bfr[j], acc[i][j], 0, 0, 0);
    }
    asm volatile("s_waitcnt vmcnt(0)" ::: "memory");
    __builtin_amdgcn_s_barrier();
  }

#pragma unroll
  for (int i = 0; i < 4; ++i)
#pragma unroll
    for (int j = 0; j < 4; ++j)
#pragma unroll
      for (int r = 0; r < 4; ++r) {
        int gm = bm + wm + i * 16 + quad * 4 + r;
        int gn = bn + wn + j * 16 + l16;
        if (gm < D.M && gn < D.N) D.C[(size_t)gm * D.ldc + gn] = (bf16_t)acc[i][j][r];
      }
}

// ---------------------------------------------------------------- fused pack + rope (vectorized, bf16x8)
__global__ __launch_bounds__(256) void pack_qk_k(const bf16_t* __restrict__ qcat,
                                                 const bf16_t* __restrict__ khead,
                                                 const bf16_t* __restrict__ xa,
                                                 const bf16_t* __restrict__ fc,
                                                 const bf16_t* __restrict__ fs,
                                                 bf16_t* __restrict__ Qp, bf16_t* __restrict__ Kp) {
  int idx = blockIdx.x * 256 + threadIdx.x;
  if (idx >= NH * T_DIM * 24) return;
  int j8 = idx % 24;                 // 24 x 8 elems = 192 per output row
  int t = (idx / 24) % T_DIM;
  int h = idx / (24 * T_DIM);
  if (blockIdx.y == 0) {
    const float scale = 0.07216878364870323f;  // 1/sqrt(HS+DHR)
    bf16_t* out = Qp + ((size_t)h * T_DIM + t) * QKD + j8 * 8;
    if (j8 < 16) {
      bf16x8 v = *(const bf16x8*)(qcat + (size_t)t * 3072 + h * HS + j8 * 8);
      bf16x8 r;
#pragma unroll
      for (int k = 0; k < 8; ++k) r[k] = (bf16_t)((float)v[k] * scale);
      *(bf16x8*)out = r;
    } else {
      int i0 = (j8 - 16) * 4;        // 4 rope pairs
      bf16x8 v = *(const bf16x8*)(qcat + (size_t)t * 3072 + 2048 + h * DHR + i0 * 2);
      bf16x4 cc = *(const bf16x4*)(fc + t * 32 + i0);
      bf16x4 ss = *(const bf16x4*)(fs + t * 32 + i0);
      bf16x8 r;
#pragma unroll
      for (int k = 0; k < 4; ++k) {
        float re = (float)v[2 * k], im = (float)v[2 * k + 1];
        float c = (float)cc[k], s = (float)ss[k];
        r[2 * k] = (bf16_t)((re * c - im * s) * scale);
        r[2 * k + 1] = (bf16_t)((re * s + im * c) * scale);
      }
      *(bf16x8*)out = r;
    }
  } else {
    bf16_t* out = Kp + ((size_t)h * T_DIM + t) * QKD + j8 * 8;
    if (j8 < 16) {
      *(bf16x8*)out = *(const bf16x8*)(khead + (size_t)t * C_DIM + h * HS + j8 * 8);
    } else {
      int i0 = (j8 - 16) * 4;
      bf16x8 v = *(const bf16x8*)(xa + (size_t)t * 2112 + 2048 + i0 * 2);
      bf16x4 cc = *(const bf16x4*)(fc + t * 32 + i0);
      bf16x4 ss = *(const bf16x4*)(fs + t * 32 + i0);
      bf16x8 r;
#pragma unroll
      for (int k = 0; k < 4; ++k) {
        float re = (float)v[2 * k], im = (float)v[2 * k + 1];
        float c = (float)cc[k], s = (float)ss[k];
        r[2 * k] = (bf16_t)(re * c - im * s);
        r[2 * k + 1] = (bf16_t)(re * s + im * c);
      }
      *(bf16x8*)out = r;
    }
  }
}

// ---------------------------------------------------------------- flash attention
// Round-3 verified structure (62.3 us): S^T orientation, 4 waves x 32 t-rows,
// FBM=128, FBN=64, balanced KV-split (<=12 tiles), reg-staged double-buffer,
// Psm per-wave staging. NO setprio: 4 barrier-lockstep waves are the m190
// regime where setprio is negative (round-7 measured +13 us regression).
#define FBM 128
#define FBN 64
#define KPITCH 200
#define VPITCH 72
#define PPITCH 72

__global__ __launch_bounds__(256) void flash_k(const bf16_t* __restrict__ Qp,
                                               const bf16_t* __restrict__ Kp,
                                               const bf16_t* __restrict__ VT,
                                               void* __restrict__ Y,
                                               const bf16_t* __restrict__ xprobe,
                                               float* __restrict__ OpartA,
                                               float* __restrict__ OpartB,
                                               float* __restrict__ Mpart,
                                               float* __restrict__ Lpart) {
  __shared__ bf16_t Ksm[FBN * KPITCH];    // 25.6 KB
  __shared__ bf16_t Vtsm[HS * VPITCH];    // 18.4 KB
  __shared__ bf16_t Psm[4][32 * PPITCH];  // 18.4 KB
  const int tid = threadIdx.x;
  const int lane = tid & 63, wave = tid >> 6;  // wave 0..3, 32 t-rows each
  const int l16 = lane & 15, quad = lane >> 4;
  const int id = blockIdx.x;
  const int xcd = id & 7, slot = id >> 3;
  const int h = xcd + 8 * (slot / 30);
  const int p = slot % 30;
  const int qt = c_qt_tab[p];
  const int part = c_pt_tab[p];
  const int nkv = 2 * qt + 2;
  const int nparts = (qt <= 5) ? 1 : (qt <= 11 ? 2 : 3);
  const int bse = nkv / nparts, rem = nkv % nparts;
  const int kt0 = part * bse + (part < rem ? part : rem);
  const int kt1 = kt0 + bse + (part < rem ? 1 : 0);
  const int partial = (nparts > 1);
  const int qb = qt * FBM;
  const int f32out = probe_f32(xprobe);
  const float L2E = 1.4426950408889634f;

  // Q fragments: two 16-row t-tiles per wave (B-operand: n=l16 rows)
  bf16x8 aq[2][6];
#pragma unroll
  for (int tt = 0; tt < 2; ++tt) {
    const bf16_t* qbase = Qp + ((size_t)h * T_DIM + qb + wave * 32 + tt * 16 + l16) * QKD;
#pragma unroll
    for (int c = 0; c < 6; ++c) aq[tt][c] = *(const bf16x8*)(qbase + c * 32 + quad * 8);
  }

  f32x4 o[2][8] = {};           // O^T: rows d (8 tiles), cols t (l16); [tt]
  float m_i[2] = {-3.0e38f, -3.0e38f}, l_i[2] = {0.f, 0.f};

  const bf16_t* kg_base = Kp + (size_t)h * T_DIM * QKD;
  const bf16_t* vg_base = VT + (size_t)(h * HS) * T_DIM;

  // register prefetch (6 K-chunks + 4 V-chunks per thread, 256 threads)
  bf16x8 kreg[6], vreg[4];
  {
    const bf16_t* kg = kg_base + (size_t)kt0 * FBN * QKD;
#pragma unroll
    for (int i = 0; i < 6; ++i) {
      int idx = i * 256 + tid;  // 64 rows * 24 vec8
      kreg[i] = *(const bf16x8*)(kg + (size_t)idx * 8);
    }
    const bf16_t* vg = vg_base + kt0 * FBN;
#pragma unroll
    for (int i = 0; i < 4; ++i) {
      int idx = i * 256 + tid, row = idx >> 3, c8 = idx & 7;
      vreg[i] = *(const bf16x8*)(vg + (size_t)row * T_DIM + c8 * 8);
    }
  }

  for (int kt = kt0; kt < kt1; ++kt) {
    __syncthreads();  // previous compute done -> LDS writable
#pragma unroll
    for (int i = 0; i < 6; ++i) {
      int idx = i * 256 + tid, row = idx / 24, c8 = idx % 24;
      *(bf16x8*)(Ksm + row * KPITCH + c8 * 8) = kreg[i];
    }
#pragma unroll
    for (int i = 0; i < 4; ++i) {
      int idx = i * 256 + tid, row = idx >> 3, c8 = idx & 7;
      *(bf16x8*)(Vtsm + row * VPITCH + c8 * 8) = vreg[i];
    }
    __syncthreads();  // LDS ready
    if (kt + 1 < kt1) {
      const bf16_t* kg = kg_base + (size_t)(kt + 1) * FBN * QKD;
#pragma unroll
      for (int i = 0; i < 6; ++i) {
        int idx = i * 256 + tid;
        kreg[i] = *(const bf16x8*)(kg + (size_t)idx * 8);
      }
      const bf16_t* vg = vg_base + (kt + 1) * FBN;
#pragma unroll
      for (int i = 0; i < 4; ++i) {
        int idx = i * 256 + tid, row = idx >> 3, c8 = idx & 7;
        vreg[i] = *(const bf16x8*)(vg + (size_t)row * T_DIM + c8 * 8);
      }
    }
    // S^T = K @ Q^T : rows s (4 tiles of 16), cols t (2 tiles, l16)
    f32x4 sc[2][4] = {};
#pragma unroll
    for (int nt = 0; nt < 4; ++nt)
#pragma unroll
      for (int c = 0; c < 6; ++c) {
        bf16x8 bk = *(const bf16x8*)(Ksm + (nt * 16 + l16) * KPITCH + c * 32 + quad * 8);
        sc[0][nt] = __builtin_amdgcn_mfma_f32_16x16x32_bf16(bk, aq[0][c], sc[0][nt], 0, 0, 0);
        sc[1][nt] = __builtin_amdgcn_mfma_f32_16x16x32_bf16(bk, aq[1][c], sc[1][nt], 0, 0, 0);
      }
    if (kt >= 2 * qt) {  // diagonal region
#pragma unroll
      for (int tt = 0; tt < 2; ++tt) {
        int t_glob = qb + wave * 32 + tt * 16 + l16;
#pragma unroll
        for (int nt = 0; nt < 4; ++nt) {
          int s_base = kt * FBN + nt * 16 + quad * 4;
#pragma unroll
          for (int r = 0; r < 4; ++r)
            if (s_base + r > t_glob) sc[tt][nt][r] = -3.0e38f;
        }
      }
    }
    // online softmax per t-column (l16); defer-max (T13): skip rescale unless
    // the new tile max exceeds the running max by >5.5.
#pragma unroll
    for (int tt = 0; tt < 2; ++tt) {
      float mx = sc[tt][0][0];
#pragma unroll
      for (int nt = 0; nt < 4; ++nt)
#pragma unroll
        for (int r = 0; r < 4; ++r) mx = fmaxf(mx, sc[tt][nt][r]);
      mx = fmaxf(mx, __shfl_xor(mx, 16, 64));
      mx = fmaxf(mx, __shfl_xor(mx, 32, 64));
      int need = (mx > m_i[tt] + 5.5f) ? 1 : 0;
      if (__any(need)) {
        float mn = fmaxf(m_i[tt], mx);
        float alpha = fexp2((m_i[tt] - mn) * L2E);
        m_i[tt] = mn;
        l_i[tt] *= alpha;
#pragma unroll
        for (int dt = 0; dt < 8; ++dt) o[tt][dt] *= alpha;
      }
      float rs = 0.f;
#pragma unroll
      for (int nt = 0; nt < 4; ++nt) {
        float p0 = fexp2((sc[tt][nt][0] - m_i[tt]) * L2E);
        float p1 = fexp2((sc[tt][nt][1] - m_i[tt]) * L2E);
        float p2 = fexp2((sc[tt][nt][2] - m_i[tt]) * L2E);
        float p3 = fexp2((sc[tt][nt][3] - m_i[tt]) * L2E);
        rs += (p0 + p1) + (p2 + p3);
        uint2 pk;
        asm("v_cvt_pk_bf16_f32 %0, %1, %2" : "=v"(pk.x) : "v"(p0), "v"(p1));
        asm("v_cvt_pk_bf16_f32 %0, %1, %2" : "=v"(pk.y) : "v"(p2), "v"(p3));
        *(uint2*)(&Psm[wave][(tt * 16 + l16) * PPITCH + nt * 16 + quad * 4]) = pk;
      }
      rs += __shfl_xor(rs, 16, 64);
      rs += __shfl_xor(rs, 32, 64);
      l_i[tt] += rs;
    }
    // O^T += V^T @ P^T (per-wave Psm, no extra barrier)
#pragma unroll
    for (int s2 = 0; s2 < 2; ++s2) {
      bf16x8 ap0 = *(const bf16x8*)(&Psm[wave][l16 * PPITCH + s2 * 32 + quad * 8]);
      bf16x8 ap1 = *(const bf16x8*)(&Psm[wave][(16 + l16) * PPITCH + s2 * 32 + quad * 8]);
#pragma unroll
      for (int dt = 0; dt < 8; ++dt) {
        bf16x8 bv = *(const bf16x8*)(Vtsm + (dt * 16 + l16) * VPITCH + s2 * 32 + quad * 8);
        o[0][dt] = __builtin_amdgcn_mfma_f32_16x16x32_bf16(bv, ap0, o[0][dt], 0, 0, 0);
        o[1][dt] = __builtin_amdgcn_mfma_f32_16x16x32_bf16(bv, ap1, o[1][dt], 0, 0, 0);
      }
    }
  }

  if (!partial) {
#pragma unroll
    for (int tt = 0; tt < 2; ++tt) {
      float inv = 1.0f / l_i[tt];
      int t = qb + wave * 32 + tt * 16 + l16;
#pragma unroll
      for (int dt = 0; dt < 8; ++dt) {
        size_t oi = (size_t)t * C_DIM + h * HS + dt * 16 + quad * 4;
        if (f32out) {
          f32x4 v;
#pragma unroll
          for (int r = 0; r < 4; ++r) v[r] = o[tt][dt][r] * inv;
          *(f32x4*)((float*)Y + oi) = v;
        } else {
          bf16x4 v;
#pragma unroll
          for (int r = 0; r < 4; ++r) v[r] = (bf16_t)(o[tt][dt][r] * inv);
          *(bf16x4*)((bf16_t*)Y + oi) = v;
        }
      }
    }
  } else {
    const int pi = h * 24 + c_pbase[qt] + part;
    float* obase = opart_at(OpartA, OpartB, pi);
#pragma unroll
    for (int tt = 0; tt < 2; ++tt) {
      int rowl = wave * 32 + tt * 16 + l16;  // 0..127
      float* ob = obase + (size_t)rowl * 128;
#pragma unroll
      for (int dt = 0; dt < 8; ++dt) {
        f32x4 v = o[tt][dt];
        *(f32x4*)(ob + dt * 16 + quad * 4) = v;
      }
      if (quad == 0) {
        Mpart[(size_t)pi * 128 + rowl] = m_i[tt];
        Lpart[(size_t)pi * 128 + rowl] = l_i[tt];
      }
    }
  }
}

// ---------------------------------------------------------------- combine partials (qt>=6)
__global__ __launch_bounds__(256) void combine_k(const float* __restrict__ OpartA,
                                                 const float* __restrict__ OpartB,
                                                 const float* __restrict__ Mpart,
                                                 const float* __restrict__ Lpart,
                                                 void* __restrict__ Y,
                                                 const bf16_t* __restrict__ xprobe) {
  const int h = blockIdx.y;
  const int qt = 6 + blockIdx.x;       // 6..15
  const int c = (qt <= 11) ? 2 : 3;
  const int pib = h * 24 + c_pbase[qt];
  const int row = threadIdx.x >> 1;    // 0..127
  const int c0 = (threadIdx.x & 1) * 64;
  const int f32out = probe_f32(xprobe);
  const float L2E = 1.4426950408889634f;
  float m0 = Mpart[(size_t)pib * 128 + row];
  float m1 = Mpart[(size_t)(pib + 1) * 128 + row];
  float l0 = Lpart[(size_t)pib * 128 + row];
  float l1 = Lpart[(size_t)(pib + 1) * 128 + row];
  float m2 = -3.0e38f, l2 = 0.f;
  if (c == 3) {
    m2 = Mpart[(size_t)(pib + 2) * 128 + row];
    l2 = Lpart[(size_t)(pib + 2) * 128 + row];
  }
  float ms = fmaxf(m0, fmaxf(m1, m2));
  float w0 = fexp2((m0 - ms) * L2E);
  float w1 = fexp2((m1 - ms) * L2E);
  float w2 = fexp2((m2 - ms) * L2E);
  float inv = 1.0f / (l0 * w0 + l1 * w1 + l2 * w2);
  const float* O0 = opart_atc(OpartA, OpartB, pib) + (size_t)row * 128 + c0;
  const float* O1 = opart_atc(OpartA, OpartB, pib + 1) + (size_t)row * 128 + c0;
  const float* O2 = opart_atc(OpartA, OpartB, pib + 2) + (size_t)row * 128 + c0;
  int t = qt * 128 + row;
  size_t ob = (size_t)t * C_DIM + h * HS + c0;
#pragma unroll
  for (int d4 = 0; d4 < 64; d4 += 4) {
    f32x4 a = *(const f32x4*)(O0 + d4);
    f32x4 b = *(const f32x4*)(O1 + d4);
    f32x4 acc;
#pragma unroll
    for (int j = 0; j < 4; ++j) acc[j] = a[j] * w0 + b[j] * w1;
    if (c == 3) {
      f32x4 e = *(const f32x4*)(O2 + d4);
#pragma unroll
      for (int j = 0; j < 4; ++j) acc[j] += e[j] * w2;
    }
#pragma unroll
    for (int j = 0; j < 4; ++j) {
      float v = acc[j] * inv;
      if (f32out) ((float*)Y)[ob + d4 + j] = v;
      else        ((bf16_t*)Y)[ob + d4 + j] = (bf16_t)v;
    }
  }
}

// ---------------------------------------------------------------- launch
extern "C" void kernel_launch(void* const* d_in, const int* in_sizes, int n_in,
                              void* d_out, int out_size, void* d_ws, size_t ws_size,
                              hipStream_t stream) {
  bf16_t* w = (bf16_t*)d_ws;
  const bf16_t* xprobe = (const bf16_t*)d_in[0];

  if (ws_size < (size_t)34472000 * 2 + 128) return;

  // ---- workspace layout (bf16 elements), lifetime-aliased ----
  bf16_t* fcc    = w + 64;        // 65536
  bf16_t* fsc    = w + 65600;     // 65536
  bf16_t* xc     = w + 131136;    // 4194304
  bf16_t* BigB   = w + 4325440;   // 4325376 = [W_dq(1536) | W_dkv(512) | W_kr(64)] x 2048
  bf16_t* dqc    = BigB;
  bf16_t* dkvc   = BigB + 3145728;
  bf16_t* krc    = BigB + 4194304;
  bf16_t* Bq     = w + 8650816;   // 4718592 = [W_uq_t(2048) | W_qr(1024)] x 1536
  bf16_t* W_uq_t = Bq;
  bf16_t* qrc    = Bq + 3145728;
  bf16_t* xa     = w + 13369408;  // 4325376: cols [c_q(1536) | c_kv(512) | k_r(64)], ld 2112
  bf16_t* qcat   = w + 17694784;  // 6291456: cols [q_up(2048) | q_r(1024)], ld 3072
  bf16_t* k_head = w + 23986240;  // 4194304
  bf16_t* vhatT  = w + 28180544;  // 4194304
  bf16_t* ukc    = w + 32374848;  // 1048576
  bf16_t* Pt     = w + 33423424;  // 1048576
  // aliases (lifetime-disjoint)
  bf16_t* woc    = qcat;          // dead before qcat GEMM writes here
  bf16_t* W_uv_t = k_head;        // dead before k_head GEMM writes here
  bf16_t* Qpack  = xc;            // xc + BigB head; ends at elem 6422592
  bf16_t* Kpack  = qcat;          // qcat dead after pack
  // flash partials, 384 slots of 128x128 f32, split across two dead regions:
  //   region A [6422592, 17694784): slots 0..337 + Mpart/Lpart at the tail
  //   region B [23986240, 28180544) (dead k_head): slots 338..383
  float* OpartA = (float*)(w + 6422592);   // 338 slots: ends at elem 17498176
  float* Mpart  = (float*)(w + 17498176);  // 384*128 f32 -> ends 17596480
  float* Lpart  = (float*)(w + 17596480);  // -> ends 17694784 (= qcat start)
  float* OpartB = (float*)(w + 23986240);  // 46 slots: ends at elem 25493568

  // prep: 9 converts + 2 transposes, one launch
  PrepPack pp;
  const void* srcs[9] = {d_in[1], d_in[2], d_in[0], d_in[3], d_in[5], d_in[9], d_in[8], d_in[6], d_in[10]};
  bf16_t* dsts[9]     = {fcc,     fsc,     xc,      dqc,     dkvc,    krc,     qrc,     ukc,     woc};
  int ns[9] = {T_DIM * 32, T_DIM * 32, T_DIM * C_DIM, NLQ * C_DIM, NLKV * C_DIM,
               DHR * C_DIM, NH * DHR * NLQ, C_DIM * NLKV, C_DIM * C_DIM};
  for (int i = 0; i < 9; ++i) { pp.src[i] = srcs[i]; pp.dst[i] = dsts[i]; pp.n[i] = ns[i]; }
  pp.tsrc[0] = d_in[4]; pp.tdst[0] = W_uq_t; pp.tR[0] = 1536; pp.tC[0] = 2048; pp.tbx[0] = 64;
  pp.tsrc[1] = d_in[7]; pp.tdst[1] = W_uv_t; pp.tR[1] = 2048; pp.tC[1] = 512;  pp.tbx[1] = 16;
  prep_k<<<dim3(3072, 11), 256, 0, stream>>>(pp, xprobe);

  // G1: xa (272 blk) || Pt (64 blk)
  {
    GGrp g;
    g.d[0] = {xc,  BigB,   xa, 2048, 2112, 2048, 2048, 2048, 2112, 16, 0};
    g.d[1] = {woc, W_uv_t, Pt, 2048,  512, 2048, 2048, 2048,  512, 16, 272};
    gemm_group<<<336, 256, 0, stream>>>(g, 2);
  }
  // G2: qcat (384) || k_head (256) || vhatT (256)
  {
    GGrp g;
    g.d[0] = {xa,        Bq,        qcat,   2048, 3072, 1536, 2112, 1536, 3072, 16, 0};
    g.d[1] = {xa + 1536, ukc,       k_head, 2048, 2048,  512, 2112,  512, 2048, 16, 384};
    g.d[2] = {Pt,        xa + 1536, vhatT,  2048, 2048,  512,  512, 2112, 2048, 16, 640};
    gemm_group<<<896, 256, 0, stream>>>(g, 3);
  }

  pack_qk_k<<<dim3(3072, 2), 256, 0, stream>>>(qcat, k_head, xa, fcc, fsc, Qpack, Kpack);

  flash_k<<<dim3(480), 256, 0, stream>>>(Qpack, Kpack, vhatT, d_out, xprobe,
                                         OpartA, OpartB, Mpart, Lpart);
  combine_k<<<dim3(10, NH), 256, 0, stream>>>(OpartA, OpartB, Mpart, Lpart, d_out, xprobe);
}